// Round 9
// baseline (6371.542 us; speedup 1.0000x reference)
//
#include <hip/hip_runtime.h>
#include <cstdint>

// AttentionDecoder: B=128, L=196, T_dec=31, E=H=F=A=512, V=10000
// Out: logits (128*31*10000) | alphas (128*31*196) | dec_len (128), fp32.

#define DEV __device__ __forceinline__

typedef __bf16 bf16x8 __attribute__((ext_vector_type(8)));
typedef float  f32x4  __attribute__((ext_vector_type(4)));
typedef unsigned short us8 __attribute__((ext_vector_type(8)));
typedef unsigned short us4v __attribute__((ext_vector_type(4)));

DEV float sigmf(float v) { return 1.f / (1.f + expf(-v)); }

DEV ushort f2bf(float f) {
  union { float f; uint32_t u; } c; c.f = f;
  uint32_t u = c.u;
  return (ushort)((u + 0x7FFFu + ((u >> 16) & 1u)) >> 16);
}
DEV float bf2f(ushort h) {
  union { uint32_t u; float f; } c; c.u = ((uint32_t)h) << 16;
  return c.f;
}
DEV void cvt8(const float* __restrict__ s, ushort* __restrict__ d) {
  float4 a = *(const float4*)s;
  float4 b = *(const float4*)(s + 4);
  ushort4 lo = make_ushort4(f2bf(a.x), f2bf(a.y), f2bf(a.z), f2bf(a.w));
  ushort4 hi = make_ushort4(f2bf(b.x), f2bf(b.y), f2bf(b.z), f2bf(b.w));
  *(ushort4*)d = lo;
  *(ushort4*)(d + 4) = hi;
}

// Software grid barrier (validated in round 5: passed correctness with these
// exact atomic idioms). bar[0]=count, bar[64]=generation.
DEV void gbar(unsigned* bar, unsigned nblk) {
  __syncthreads();
  if (threadIdx.x == 0) {
    unsigned* cnt = bar;
    unsigned* gen = bar + 64;
    unsigned g = __hip_atomic_load(gen, __ATOMIC_RELAXED, __HIP_MEMORY_SCOPE_AGENT);
    unsigned a = __hip_atomic_fetch_add(cnt, 1u, __ATOMIC_ACQ_REL,
                                        __HIP_MEMORY_SCOPE_AGENT);
    if (a == nblk - 1u) {
      __hip_atomic_store(cnt, 0u, __ATOMIC_RELAXED, __HIP_MEMORY_SCOPE_AGENT);
      __hip_atomic_store(gen, g + 1u, __ATOMIC_RELEASE, __HIP_MEMORY_SCOPE_AGENT);
    } else {
      while (__hip_atomic_load(gen, __ATOMIC_ACQUIRE,
                               __HIP_MEMORY_SCOPE_AGENT) == g)
        __builtin_amdgcn_s_sleep(2);
    }
  }
  __syncthreads();
}

// ---------------------------------------------------------------------------
// 4-wave 128x128 MFMA body (standalone kernels: annp GEMM, logits, init).
DEV void mfma_body(ushort* As, ushort* Ws, int mt, int nt,
                   const ushort* __restrict__ A, int lda,
                   const ushort* __restrict__ W, int ldw,
                   int K, int mode, const float* __restrict__ bias,
                   float* __restrict__ Cf, ushort* __restrict__ Cb, int ldc,
                   int Ncols, const int* __restrict__ declen)
{
  const int tid = threadIdx.x;
  const int m0 = mt * 128, n0 = nt * 128;
  const int wv = tid >> 6, lane = tid & 63;
  const int rw = (wv & 1) * 64, cw = (wv >> 1) * 64;
  const int lrow = lane & 15, lk = (lane >> 4) * 8;
  f32x4 acc[4][4];
#pragma unroll
  for (int i = 0; i < 4; ++i)
#pragma unroll
    for (int j = 0; j < 4; ++j) acc[i][j] = (f32x4){0.f, 0.f, 0.f, 0.f};

  const int srow = tid >> 3;
  const int sc8  = tid & 7;
  for (int k0 = 0; k0 < K; k0 += 64) {
    __syncthreads();
#pragma unroll
    for (int it = 0; it < 4; ++it) {
      int row = it * 32 + srow;
      *(uint4*)&As[row * 72 + sc8 * 8] =
          *(const uint4*)&A[(size_t)(m0 + row) * lda + k0 + sc8 * 8];
      *(uint4*)&Ws[row * 72 + sc8 * 8] =
          *(const uint4*)&W[(size_t)(n0 + row) * ldw + k0 + sc8 * 8];
    }
    __syncthreads();
#pragma unroll
    for (int ks = 0; ks < 64; ks += 32) {
      bf16x8 af[4], bfr[4];
#pragma unroll
      for (int i = 0; i < 4; ++i)
        af[i] = *(const bf16x8*)&As[(rw + i * 16 + lrow) * 72 + ks + lk];
#pragma unroll
      for (int j = 0; j < 4; ++j)
        bfr[j] = *(const bf16x8*)&Ws[(cw + j * 16 + lrow) * 72 + ks + lk];
#pragma unroll
      for (int i = 0; i < 4; ++i)
#pragma unroll
        for (int j = 0; j < 4; ++j)
          acc[i][j] = __builtin_amdgcn_mfma_f32_16x16x32_bf16(af[i], bfr[j],
                                                              acc[i][j], 0, 0, 0);
    }
  }
  const int rsub = (lane >> 4) * 4;
#pragma unroll
  for (int i = 0; i < 4; ++i) {
#pragma unroll
    for (int j = 0; j < 4; ++j) {
      int col = n0 + cw + j * 16 + lrow;
#pragma unroll
      for (int r = 0; r < 4; ++r) {
        int row = m0 + rw + i * 16 + rsub + r;
        float v = acc[i][j][r];
        if (mode == 0) {
          Cf[(size_t)row * ldc + col] = bias ? v + bias[col] : v;
        } else if (mode == 1) {
          Cb[(size_t)row * ldc + col] = f2bf(v);
        } else {
          int tt = row >> 7, bb = row & 127;
          if (col < Ncols) {
            float o = (tt < declen[bb]) ? v + bias[col] : 0.f;
            Cf[((size_t)bb * 31 + tt) * 10000 + col] = o;
          }
        }
      }
    }
  }
}

__global__ __launch_bounds__(256) void k_mfma(
    const ushort* __restrict__ A, int lda, const ushort* __restrict__ W, int ldw,
    int K, int mode, const float* __restrict__ bias,
    float* __restrict__ Cf, ushort* __restrict__ Cb, int ldc, int Ncols,
    const int* __restrict__ declen)
{
  __shared__ ushort As[128 * 72];
  __shared__ ushort Ws[128 * 72];
  mfma_body(As, Ws, blockIdx.y, blockIdx.x, A, lda, W, ldw, K, mode, bias,
            Cf, Cb, ldc, Ncols, declen);
}

__global__ __launch_bounds__(256) void k_logits(
    const ushort* __restrict__ preA, const ushort* __restrict__ Wo,
    const float* __restrict__ b_out, float* __restrict__ out_logits,
    const int* __restrict__ declen)
{
  __shared__ ushort As[128 * 72];
  __shared__ ushort Ws[128 * 72];
  int id = blockIdx.x;
  int x = id & 7, g = id >> 3;
  int G = g / 31, row = g - G * 31;
  int col = G * 8 + x;
  if (col >= 79) return;
  mfma_body(As, Ws, row, col, preA, 512, Wo, 512, 512, 3, b_out,
            out_logits, nullptr, 10000, 10000, declen);
}

// tailhg standalone (init hp/gp from h0), 4-wave body, 32 blocks x 256 thr.
__global__ __launch_bounds__(256) void k_tailhg(
    const ushort* __restrict__ x_cur, const ushort* __restrict__ Whg,
    float* __restrict__ hgP)
{
  __shared__ ushort As[128 * 72];
  __shared__ ushort Ws[128 * 72];
  int task = blockIdx.x;
  int nt = task & 7, ks = task >> 3;
  mfma_body(As, Ws, 0, nt, x_cur + 1024 + ks * 128, 1536, Whg + ks * 128, 512,
            128, 0, nullptr, hgP + (size_t)ks * 131072, nullptr, 1024, 1024,
            nullptr);
}

// ---------------------------------------------------------------------------
// 16-wave 128x128 MFMA body (in-k_steps GEMM tasks; 1024 thr, m0=0, fp32 out).
DEV void mfma16(ushort* As, ushort* Ws, int nt,
                const ushort* __restrict__ A, int lda,
                const ushort* __restrict__ W, int ldw,
                int K, float* __restrict__ Cf, int ldc)
{
  const int tid = threadIdx.x;
  const int n0 = nt * 128;
  const int wv = tid >> 6, lane = tid & 63;
  const int rw = (wv & 3) * 32, cw = (wv >> 2) * 32;
  const int lrow = lane & 15, lk = (lane >> 4) * 8;
  f32x4 acc[2][2];
#pragma unroll
  for (int i = 0; i < 2; ++i)
#pragma unroll
    for (int j = 0; j < 2; ++j) acc[i][j] = (f32x4){0.f, 0.f, 0.f, 0.f};

  const int srow = tid >> 3;   // 0..127 (1024 thr)
  const int sc8  = tid & 7;
  for (int k0 = 0; k0 < K; k0 += 64) {
    __syncthreads();
    *(uint4*)&As[srow * 72 + sc8 * 8] =
        *(const uint4*)&A[(size_t)srow * lda + k0 + sc8 * 8];
    *(uint4*)&Ws[srow * 72 + sc8 * 8] =
        *(const uint4*)&W[(size_t)(n0 + srow) * ldw + k0 + sc8 * 8];
    __syncthreads();
#pragma unroll
    for (int ks = 0; ks < 64; ks += 32) {
      bf16x8 af[2], bfr[2];
#pragma unroll
      for (int i = 0; i < 2; ++i)
        af[i] = *(const bf16x8*)&As[(rw + i * 16 + lrow) * 72 + ks + lk];
#pragma unroll
      for (int j = 0; j < 2; ++j)
        bfr[j] = *(const bf16x8*)&Ws[(cw + j * 16 + lrow) * 72 + ks + lk];
#pragma unroll
      for (int i = 0; i < 2; ++i)
#pragma unroll
        for (int j = 0; j < 2; ++j)
          acc[i][j] = __builtin_amdgcn_mfma_f32_16x16x32_bf16(af[i], bfr[j],
                                                              acc[i][j], 0, 0, 0);
    }
  }
  const int rsub = (lane >> 4) * 4;
#pragma unroll
  for (int i = 0; i < 2; ++i)
#pragma unroll
    for (int j = 0; j < 2; ++j) {
      int col = n0 + cw + j * 16 + lrow;
#pragma unroll
      for (int r = 0; r < 4; ++r) {
        int row = rw + i * 16 + rsub + r;
        Cf[(size_t)row * ldc + col] = acc[i][j][r];
      }
    }
}

// ---------------------------------------------------------------------------
// Persistent step loop: 256 blocks x 1024 threads (16 waves, <=128 VGPR,
// one block/CU — all 256 resident, barrier-safe). Block (b=bid&127,
// half=bid>>7). 5 phases/step:
//  P1 scores-half (reduce over a-half) + preA[t-1] combine (f-half)
//  P2 softmax(dup) + alpha-out(l-half) + ctx(f-half) + gate + x_cur write
//  P3 gates GEMM (blocks 0-127: 16 nt x 8 ks, 16-wave tiles)
//  P4 lstm (tid<256/block)
//  P5 tailhg (blk 0-31, skip t=30) + pre (blk 32-63)
__global__ __launch_bounds__(1024) void k_steps(
    const ushort* __restrict__ annp_bf, const ushort* __restrict__ ann_bf,
    float* __restrict__ hgP, float* __restrict__ preP, float* __restrict__ scP,
    const float* __restrict__ b_hf, const float* __restrict__ b_beta,
    const float* __restrict__ wv, const float* __restrict__ bv,
    const int* __restrict__ captions, const float* __restrict__ E_emb,
    const int* __restrict__ declen, ushort* __restrict__ x_cur,
    ushort* __restrict__ preA_bf, float* __restrict__ out_alpha,
    const ushort* __restrict__ Wg, float* __restrict__ gP,
    const float* __restrict__ biascR, float* __restrict__ cbuf,
    const ushort* __restrict__ Whg, const ushort* __restrict__ Wcat2,
    unsigned* bar)
{
  __shared__ ushort As[128 * 72];
  __shared__ ushort Ws[128 * 72];
  __shared__ float s_hp[256];
  __shared__ float s_sc[200];
  __shared__ float s_red[32];
  __shared__ float ctxacc[16 * 256];

  const int bid = blockIdx.x;
  const int b = bid & 127, half = bid >> 7;
  const int tid = threadIdx.x, lane = tid & 63, wvx = tid >> 6;
  const float bvv = bv[0];

  for (int t = 0; t < 31; ++t) {
    // ---- P1: score partials over a-half + preA[t-1] combine ----
    if (tid < 256) {
      int a = half * 256 + tid;
      int o = b * 1024 + a;
      s_hp[tid] = b_hf[a] + hgP[o] + hgP[131072 + o] + hgP[262144 + o]
                + hgP[393216 + o];
      if (t > 0) {
        int o2 = b * 512 + a;
        float s = 0.f;
#pragma unroll
        for (int ks = 0; ks < 8; ++ks) s += preP[ks * 65536 + o2];
        preA_bf[((size_t)(t - 1) * 128 + b) * 512 + a] = f2bf(tanhf(s));
      }
    }
    __syncthreads();
    {
      float hp4[4], wt4[4];
      int a0 = half * 256 + lane * 4;
#pragma unroll
      for (int i = 0; i < 4; ++i) {
        hp4[i] = s_hp[lane * 4 + i];
        wt4[i] = wv[a0 + i];
      }
      const ushort* ap = annp_bf + (size_t)b * 196 * 512 + a0;
      us4v v[13];
#pragma unroll
      for (int k = 0; k < 13; ++k) {
        int l = wvx + 16 * k;
        int lc = (l < 196) ? l : 0;
        v[k] = *(const us4v*)(ap + (size_t)lc * 512);
      }
      float outk[13];
#pragma unroll
      for (int k = 0; k < 13; ++k) {
        float acc = 0.f;
#pragma unroll
        for (int i = 0; i < 4; ++i)
          acc = fmaf(fmaxf(bf2f(v[k][i]) + hp4[i], 0.f), wt4[i], acc);
#pragma unroll
        for (int off = 32; off; off >>= 1) acc += __shfl_xor(acc, off, 64);
        outk[k] = acc;
      }
      if (lane == 0) {
#pragma unroll
        for (int k = 0; k < 13; ++k) {
          int l = wvx + 16 * k;
          if (l < 196) scP[half * 25088 + b * 196 + l] = outk[k];
        }
      }
    }
    gbar(bar, 256);

    // ---- P2: softmax (dup per half) + alpha out + ctx f-half + x_cur ----
    {
      float vsc = -3.402823466e38f;
      if (tid < 196) {
        int o = b * 196 + tid;
        vsc = scP[o] + scP[25088 + o] + bvv;
      }
      float m = vsc;
#pragma unroll
      for (int off = 32; off; off >>= 1) m = fmaxf(m, __shfl_xor(m, off, 64));
      if (lane == 0) s_red[wvx] = m;
      __syncthreads();
      m = s_red[0];
#pragma unroll
      for (int i = 1; i < 16; ++i) m = fmaxf(m, s_red[i]);
      float e = (tid < 196) ? expf(vsc - m) : 0.f;
      float ssum = e;
#pragma unroll
      for (int off = 32; off; off >>= 1) ssum += __shfl_xor(ssum, off, 64);
      if (lane == 0) s_red[16 + wvx] = ssum;
      __syncthreads();
      float s = 0.f;
#pragma unroll
      for (int i = 0; i < 16; ++i) s += s_red[16 + i];
      float inv = 1.f / s;
      bool active = t < declen[b];
      if (tid < 196) {
        float al = e * inv;
        s_sc[tid] = al;
        if (tid >= half * 98 && tid < half * 98 + 98)
          out_alpha[((size_t)b * 31 + t) * 196 + tid] = active ? al : 0.f;
      }
      __syncthreads();
      // ctx over all l for f-half; wave wvx owns rows l = wvx + 16k
      int f0 = half * 256 + lane * 4;
      const ushort* ab = ann_bf + (size_t)b * 196 * 512 + f0;
      us4v v[13];
      float alf[13];
#pragma unroll
      for (int k = 0; k < 13; ++k) {
        int l = wvx + 16 * k;
        int lc = (l < 196) ? l : 0;
        v[k] = *(const us4v*)(ab + (size_t)lc * 512);
        alf[k] = (l < 196) ? s_sc[l] : 0.f;
      }
      float c4[4] = {0.f, 0.f, 0.f, 0.f};
#pragma unroll
      for (int k = 0; k < 13; ++k)
#pragma unroll
        for (int i = 0; i < 4; ++i)
          c4[i] = fmaf(alf[k], bf2f(v[k][i]), c4[i]);
      *(float4*)&ctxacc[wvx * 256 + lane * 4] =
          make_float4(c4[0], c4[1], c4[2], c4[3]);
      __syncthreads();
      if (tid < 256) {
        float ctx = 0.f;
#pragma unroll
        for (int w = 0; w < 16; ++w) ctx += ctxacc[w * 256 + tid];
        int fg = half * 256 + tid;
        int o2 = b * 1024 + 512 + fg;
        float g = sigmf(hgP[o2] + hgP[131072 + o2] + hgP[262144 + o2]
                        + hgP[393216 + o2] + b_beta[fg]);
        int tok = captions[b * 32 + t];
        x_cur[b * 1536 + 512 + fg] = f2bf(g * ctx);
        x_cur[b * 1536 + fg] = f2bf(E_emb[(size_t)tok * 512 + fg]);
      }
    }
    gbar(bar, 256);

    // ---- P3: gates GEMM (128 tasks = 16 nt x 8 ks, K=192) ----
    if (bid < 128) {
      int nt = bid & 15, ks = bid >> 4;
      mfma16(As, Ws, nt, x_cur + ks * 192, 1536, Wg + ks * 192, 1536, 192,
             gP + (size_t)ks * 262144, 2048);
    }
    gbar(bar, 256);

    // ---- P4: lstm (tid<256/block; idx covers 65536) ----
    if (tid < 256) {
      int idx = bid * 256 + tid;
      int bb = idx >> 9, f = idx & 511;
      if (t < declen[bb]) {
        float4 v4 = make_float4(0.f, 0.f, 0.f, 0.f);
#pragma unroll
        for (int ks = 0; ks < 8; ++ks) {
          float4 pv = *(const float4*)&gP[(size_t)ks * 262144 + bb * 2048 + f * 4];
          v4.x += pv.x; v4.y += pv.y; v4.z += pv.z; v4.w += pv.w;
        }
        float4 bc = *(const float4*)&biascR[f * 4];
        float i_ = v4.x + bc.x, f_ = v4.y + bc.y, g_ = v4.z + bc.z,
              o_ = v4.w + bc.w;
        float cn = sigmf(f_) * cbuf[idx] + sigmf(i_) * tanhf(g_);
        float hn = sigmf(o_) * tanhf(cn);
        cbuf[idx] = cn;
        x_cur[bb * 1536 + 1024 + f] = f2bf(hn);
      }
    }
    gbar(bar, 256);

    // ---- P5: tailhg (0-31, skip t=30) + pre (32-63) ----
    if (bid < 32) {
      if (t < 30) {
        int nt = bid & 7, ks = bid >> 3;
        mfma16(As, Ws, nt, x_cur + 1024 + ks * 128, 1536, Whg + ks * 128, 512,
               128, hgP + (size_t)ks * 131072, 1024);
      }
    } else if (bid < 64) {
      int j = bid - 32;
      int nt = j & 3, ks = j >> 2;
      mfma16(As, Ws, nt, x_cur + ks * 192, 1536, Wcat2 + ks * 192, 1536, 192,
             preP + (size_t)ks * 65536, 512);
    }
    gbar(bar, 256);
  }

  // epilogue: combine pre partials for t=30 (each (b,half) does its f-slice).
  if (tid < 256) {
    int f = half * 256 + tid;
    int o = b * 512 + f;
    float s = 0.f;
#pragma unroll
    for (int ks = 0; ks < 8; ++ks) s += preP[ks * 65536 + o];
    preA_bf[((size_t)30 * 128 + b) * 512 + f] = f2bf(tanhf(s));
  }
}

// ---------------------------------------------------------------------------
// Prep: weight conversions. Wg is gate-interleaved: row f*4+g <- orig row
// g*512+f of [W_ih|W_hh]; biascR likewise. Whg = [W_att_h ; W_beta].
__global__ __launch_bounds__(256) void k_prep(
    const float* __restrict__ W_ih, const float* __restrict__ W_hh,
    const float* __restrict__ b_ih, const float* __restrict__ b_hh,
    const float* __restrict__ W_y, const float* __restrict__ W_h,
    const float* __restrict__ W_z, const float* __restrict__ W_out,
    const float* __restrict__ W_att_f, const float* __restrict__ W_att_h,
    const float* __restrict__ W_beta, const float* __restrict__ b_att_f,
    const float* __restrict__ b_att_h, const float* __restrict__ ann,
    ushort* __restrict__ Wg, ushort* __restrict__ Wcat2_bf,
    ushort* __restrict__ Wo_bf, ushort* __restrict__ Waf_bf,
    ushort* __restrict__ Whg_bf, ushort* __restrict__ ann_bf,
    float* __restrict__ biascR, float* __restrict__ b_hf)
{
  int idx = blockIdx.x * 256 + threadIdx.x;
  int stride = gridDim.x * 256;
  for (int i = idx; i < 12845056 / 8; i += stride)
    cvt8(ann + (size_t)i * 8, ann_bf + (size_t)i * 8);
  for (int i = idx; i < 3145728 / 8; i += stride) {
    int k8 = i * 8, rp = k8 / 1536, c = k8 - rp * 1536;
    int f = rp >> 2, g = rp & 3;
    int r = g * 512 + f;
    const float* src = (c < 1024) ? (W_ih + (size_t)r * 1024 + c)
                                  : (W_hh + (size_t)r * 512 + c - 1024);
    cvt8(src, Wg + k8);
  }
  for (int i = idx; i < 786432 / 8; i += stride) {
    int k8 = i * 8, r = k8 / 1536, c = k8 - r * 1536;
    const float* src = (c < 512) ? (W_y + (size_t)r * 512 + c)
                     : (c < 1024 ? (W_z + (size_t)r * 512 + c - 512)
                                 : (W_h + (size_t)r * 512 + c - 1024));
    cvt8(src, Wcat2_bf + k8);
  }
  for (int i = idx; i < 5177344 / 8; i += stride) {   // Wo: 10112x512, pad 0
    int r = i >> 6, c8 = i & 63;
    if (r < 10000) cvt8(W_out + (size_t)r * 512 + c8 * 8, Wo_bf + (size_t)i * 8);
    else { *(uint4*)(Wo_bf + (size_t)i * 8) = make_uint4(0, 0, 0, 0); }
  }
  for (int i = idx; i < 262144 / 8; i += stride)
    cvt8(W_att_f + i * 8, Waf_bf + i * 8);
  for (int i = idx; i < 524288 / 8; i += stride) {    // Whg: 1024x512
    int r = i >> 6, c8 = i & 63;
    const float* src = (r < 512) ? (W_att_h + (size_t)r * 512 + c8 * 8)
                                 : (W_beta + (size_t)(r - 512) * 512 + c8 * 8);
    cvt8(src, Whg_bf + (size_t)i * 8);
  }
  for (int i = idx; i < 2048; i += stride) {
    int f = i >> 2, g = i & 3;
    biascR[i] = b_ih[g * 512 + f] + b_hh[g * 512 + f];
  }
  for (int i = idx; i < 512; i += stride) b_hf[i] = b_att_h[i] + b_att_f[i];
}

// mean over L, dec_len; also resets the grid-barrier state for this replay.
__global__ __launch_bounds__(256) void k_mean(
    const float* __restrict__ ann, const int* __restrict__ lengths,
    float* __restrict__ meanb, int* __restrict__ declen,
    float* __restrict__ out_dec, unsigned* bar)
{
  int b = blockIdx.x, tid = threadIdx.x;
  const float* ab = ann + (size_t)b * 196 * 512;
  for (int f = tid; f < 512; f += 256) {
    float s = 0.f;
    for (int l = 0; l < 196; ++l) s += ab[l * 512 + f];
    meanb[b * 512 + f] = s * (1.f / 196.f);
  }
  if (tid == 0) {
    int d = lengths[b] - 1;
    if (d < 1) d = 1;
    declen[b] = d;
    out_dec[b] = (float)d;
    if (b == 0) { bar[0] = 0u; bar[64] = 0u; }
  }
}

// fp32 32x64-tile GEMM for h0/c0 init (tiny).
DEV float actf(float v, int act) { return act == 2 ? tanhf(v) : v; }
__global__ __launch_bounds__(256) void gemm32_k(
    const float* __restrict__ A, int lda, const float* __restrict__ W, int ldw,
    const float* __restrict__ bias, float* __restrict__ C, int ldc, int K, int act)
{
  __shared__ float As[32 * 36];
  __shared__ float Ws[32 * 68];
  const int tid = threadIdx.x;
  const int m0 = blockIdx.y * 32, n0 = blockIdx.x * 64;
  const int tx = tid & 15, ty = tid >> 4;
  const int r0 = ty * 2, c0 = tx * 4;
  const int lr = tid >> 3, lk = (tid & 7) * 4;
  const float* Ap = A + (size_t)(m0 + lr) * lda + lk;
  const float* Wp0 = W + (size_t)(n0 + lr) * ldw + lk;
  const float* Wp1 = W + (size_t)(n0 + lr + 32) * ldw + lk;
  float acc[2][4] = {{0.f, 0.f, 0.f, 0.f}, {0.f, 0.f, 0.f, 0.f}};
  for (int k0 = 0; k0 < K; k0 += 32) {
    float4 av = *(const float4*)(Ap + k0);
    float4 w0 = *(const float4*)(Wp0 + k0);
    float4 w1 = *(const float4*)(Wp1 + k0);
    __syncthreads();
    As[(lk + 0) * 36 + lr] = av.x; As[(lk + 1) * 36 + lr] = av.y;
    As[(lk + 2) * 36 + lr] = av.z; As[(lk + 3) * 36 + lr] = av.w;
    Ws[(lk + 0) * 68 + lr] = w0.x; Ws[(lk + 1) * 68 + lr] = w0.y;
    Ws[(lk + 2) * 68 + lr] = w0.z; Ws[(lk + 3) * 68 + lr] = w0.w;
    Ws[(lk + 0) * 68 + lr + 32] = w1.x; Ws[(lk + 1) * 68 + lr + 32] = w1.y;
    Ws[(lk + 2) * 68 + lr + 32] = w1.z; Ws[(lk + 3) * 68 + lr + 32] = w1.w;
    __syncthreads();
#pragma unroll
    for (int kk = 0; kk < 32; ++kk) {
      float2 a = *(const float2*)&As[kk * 36 + r0];
      float4 w = *(const float4*)&Ws[kk * 68 + c0];
      const float aa[2] = {a.x, a.y};
      const float* wwp = (const float*)&w;
#pragma unroll
      for (int i = 0; i < 2; ++i)
#pragma unroll
        for (int j = 0; j < 4; ++j)
          acc[i][j] = fmaf(aa[i], wwp[j], acc[i][j]);
    }
  }
#pragma unroll
  for (int i = 0; i < 2; ++i)
#pragma unroll
    for (int j = 0; j < 4; ++j)
      C[(size_t)(m0 + r0 + i) * ldc + n0 + c0 + j] =
          actf(acc[i][j] + bias[n0 + c0 + j], act);
}

__global__ __launch_bounds__(256) void k_cvt_h0(
    const float* __restrict__ h0f, ushort* __restrict__ x_cur)
{
  int idx = blockIdx.x * 256 + threadIdx.x;   // 65536
  int b = idx >> 9, j = idx & 511;
  x_cur[b * 1536 + 1024 + j] = f2bf(h0f[idx]);
}

// ---------------------------------------------------------------------------
extern "C" void kernel_launch(void* const* d_in, const int* in_sizes, int n_in,
                              void* d_out, int out_size, void* d_ws, size_t ws_size,
                              hipStream_t stream)
{
  const float* ann      = (const float*)d_in[0];
  const int*   captions = (const int*)d_in[1];
  const int*   lengths  = (const int*)d_in[2];
  const float* E_emb    = (const float*)d_in[3];
  const float* W_init_h = (const float*)d_in[4];
  const float* b_init_h = (const float*)d_in[5];
  const float* W_init_c = (const float*)d_in[6];
  const float* b_init_c = (const float*)d_in[7];
  const float* W_att_f  = (const float*)d_in[8];
  const float* b_att_f  = (const float*)d_in[9];
  const float* W_att_h  = (const float*)d_in[10];
  const float* b_att_h  = (const float*)d_in[11];
  const float* w_att_v  = (const float*)d_in[12];
  const float* b_att_v  = (const float*)d_in[13];
  const float* W_beta   = (const float*)d_in[14];
  const float* b_beta   = (const float*)d_in[15];
  const float* W_ih     = (const float*)d_in[16];
  const float* W_hh     = (const float*)d_in[17];
  const float* b_ih     = (const float*)d_in[18];
  const float* b_hh     = (const float*)d_in[19];
  const float* W_y      = (const float*)d_in[20];
  const float* W_h      = (const float*)d_in[21];
  const float* W_z      = (const float*)d_in[22];
  const float* W_out    = (const float*)d_in[23];
  const float* b_out    = (const float*)d_in[24];

  float* out        = (float*)d_out;
  float* out_logits = out;
  float* out_alpha  = out + 39680000ll;
  float* out_dec    = out + 40457728ll;

  char* p = (char*)d_ws;
  auto alloc_us = [&](size_t n) { ushort* r = (ushort*)p; p += ((n * 2 + 255) & ~(size_t)255); return r; };
  auto alloc_f  = [&](size_t n) { float*  r = (float*)p;  p += ((n * 4 + 255) & ~(size_t)255); return r; };
  ushort* Wo_bf    = alloc_us(10112 * 512);
  ushort* Wg_bf    = alloc_us(2048 * 1536);
  ushort* Wcat2_bf = alloc_us(512 * 1536);
  ushort* Waf_bf   = alloc_us(512 * 512);
  ushort* Whg_bf   = alloc_us(1024 * 512);
  ushort* ann_bf   = alloc_us(12845056);
  ushort* annp_bf  = alloc_us(12845056);
  ushort* preA_bf  = alloc_us(3968 * 512);
  ushort* x_cur    = alloc_us(128 * 1536);
  float* biascR = alloc_f(2048);
  float* b_hf   = alloc_f(512);
  float* hgP    = alloc_f(4 * 131072);
  float* preP   = alloc_f(8 * 65536);
  float* scP    = alloc_f(2 * 128 * 196);
  float* gP     = alloc_f(8 * 262144);
  float* cbuf   = alloc_f(65536);
  float* meanb  = alloc_f(65536);
  float* h0f    = alloc_f(65536);
  int*   declen = (int*)alloc_f(128);
  unsigned* bar = (unsigned*)alloc_f(128);

  // ---- phase 1 ----
  hipLaunchKernelGGL(k_prep, dim3(1024), dim3(256), 0, stream,
                     W_ih, W_hh, b_ih, b_hh, W_y, W_h, W_z, W_out,
                     W_att_f, W_att_h, W_beta, b_att_f, b_att_h, ann,
                     Wg_bf, Wcat2_bf, Wo_bf, Waf_bf, Whg_bf, ann_bf,
                     biascR, b_hf);
  hipLaunchKernelGGL(k_mean, dim3(128), dim3(256), 0, stream,
                     ann, lengths, meanb, declen, out_dec, bar);
  hipLaunchKernelGGL(gemm32_k, dim3(8, 4), dim3(256), 0, stream,
                     meanb, 512, W_init_h, 512, b_init_h, h0f, 512, 512, 2);
  hipLaunchKernelGGL(gemm32_k, dim3(8, 4), dim3(256), 0, stream,
                     meanb, 512, W_init_c, 512, b_init_c, cbuf, 512, 512, 2);
  hipLaunchKernelGGL(k_cvt_h0, dim3(256), dim3(256), 0, stream, h0f, x_cur);
  hipLaunchKernelGGL(k_mfma, dim3(4, 196), dim3(256), 0, stream,
                     ann_bf, 512, Waf_bf, 512, 512, 1, (const float*)nullptr,
                     (float*)nullptr, annp_bf, 512, 512, (const int*)nullptr);
  // init hp/gp from h0
  hipLaunchKernelGGL(k_tailhg, dim3(32), dim3(256), 0, stream,
                     x_cur, Whg_bf, hgP);

  // ---- phase 2: 31 steps in one persistent kernel (software grid barrier) --
  hipLaunchKernelGGL(k_steps, dim3(256), dim3(1024), 0, stream,
                     annp_bf, ann_bf, hgP, preP, scP, b_hf, b_beta, w_att_v,
                     b_att_v, captions, E_emb, declen, x_cur, preA_bf,
                     out_alpha, Wg_bf, gP, biascR, cbuf, Whg_bf, Wcat2_bf, bar);

  // ---- phase 3: logits ----
  hipLaunchKernelGGL(k_logits, dim3(2480), dim3(256), 0, stream,
                     preA_bf, Wo_bf, b_out, out_logits, declen);
}

// Round 11
// 3425.584 us; speedup vs baseline: 1.8600x; 1.8600x over previous
//
#include <hip/hip_runtime.h>
#include <cstdint>

// AttentionDecoder: B=128, L=196, T_dec=31, E=H=F=A=512, V=10000
// Out: logits (128*31*10000) | alphas (128*31*196) | dec_len (128), fp32.

#define DEV __device__ __forceinline__

typedef __bf16 bf16x8 __attribute__((ext_vector_type(8)));
typedef float  f32x4  __attribute__((ext_vector_type(4)));
typedef unsigned short us8 __attribute__((ext_vector_type(8)));
typedef unsigned short us4v __attribute__((ext_vector_type(4)));

DEV float sigmf(float v) { return 1.f / (1.f + expf(-v)); }

DEV ushort f2bf(float f) {
  union { float f; uint32_t u; } c; c.f = f;
  uint32_t u = c.u;
  return (ushort)((u + 0x7FFFu + ((u >> 16) & 1u)) >> 16);
}
DEV float bf2f(ushort h) {
  union { uint32_t u; float f; } c; c.u = ((uint32_t)h) << 16;
  return c.f;
}
DEV void cvt8(const float* __restrict__ s, ushort* __restrict__ d) {
  float4 a = *(const float4*)s;
  float4 b = *(const float4*)(s + 4);
  ushort4 lo = make_ushort4(f2bf(a.x), f2bf(a.y), f2bf(a.z), f2bf(a.w));
  ushort4 hi = make_ushort4(f2bf(b.x), f2bf(b.y), f2bf(b.z), f2bf(b.w));
  *(ushort4*)d = lo;
  *(ushort4*)(d + 4) = hi;
}

// Software grid barrier, v2. Round-9 PMC showed the v1 ACQUIRE-spin was the
// bottleneck: every poll at agent scope emits an L2 `buffer_inv sc1` on this
// non-coherent-L2 chip, so 256 spinners continuously invalidate their XCD's
// L2 (~40 µs/barrier, and idle spinners poison workers' caches in P3/P5).
// v2: RELAXED spin (coherent at L3, no invalidation) + ONE acquire fence
// after spin exit. C++ fence-atomic sync: relaxed read of release-stored gen
// + later acquire fence => happens-before. Arrive keeps ACQ_REL fetch_add
// (release publishes this block's writes; last arriver acquires the cnt
// release-sequence => sees all blocks' writes before releasing gen).
// bar[0]=count, bar[64]=generation (separate cachelines).
DEV void gbar(unsigned* bar, unsigned nblk) {
  __syncthreads();
  if (threadIdx.x == 0) {
    unsigned* cnt = bar;
    unsigned* gen = bar + 64;
    unsigned g = __hip_atomic_load(gen, __ATOMIC_RELAXED, __HIP_MEMORY_SCOPE_AGENT);
    unsigned a = __hip_atomic_fetch_add(cnt, 1u, __ATOMIC_ACQ_REL,
                                        __HIP_MEMORY_SCOPE_AGENT);
    if (a == nblk - 1u) {
      __hip_atomic_store(cnt, 0u, __ATOMIC_RELAXED, __HIP_MEMORY_SCOPE_AGENT);
      __hip_atomic_store(gen, g + 1u, __ATOMIC_RELEASE, __HIP_MEMORY_SCOPE_AGENT);
    } else {
      while (__hip_atomic_load(gen, __ATOMIC_RELAXED,
                               __HIP_MEMORY_SCOPE_AGENT) == g)
        __builtin_amdgcn_s_sleep(4);
      __builtin_amdgcn_fence(__ATOMIC_ACQUIRE, "agent");
    }
  }
  __syncthreads();
}

// ---------------------------------------------------------------------------
// 4-wave 128x128 MFMA body (standalone kernels: annp GEMM, logits, init).
DEV void mfma_body(ushort* As, ushort* Ws, int mt, int nt,
                   const ushort* __restrict__ A, int lda,
                   const ushort* __restrict__ W, int ldw,
                   int K, int mode, const float* __restrict__ bias,
                   float* __restrict__ Cf, ushort* __restrict__ Cb, int ldc,
                   int Ncols, const int* __restrict__ declen)
{
  const int tid = threadIdx.x;
  const int m0 = mt * 128, n0 = nt * 128;
  const int wv = tid >> 6, lane = tid & 63;
  const int rw = (wv & 1) * 64, cw = (wv >> 1) * 64;
  const int lrow = lane & 15, lk = (lane >> 4) * 8;
  f32x4 acc[4][4];
#pragma unroll
  for (int i = 0; i < 4; ++i)
#pragma unroll
    for (int j = 0; j < 4; ++j) acc[i][j] = (f32x4){0.f, 0.f, 0.f, 0.f};

  const int srow = tid >> 3;
  const int sc8  = tid & 7;
  for (int k0 = 0; k0 < K; k0 += 64) {
    __syncthreads();
#pragma unroll
    for (int it = 0; it < 4; ++it) {
      int row = it * 32 + srow;
      *(uint4*)&As[row * 72 + sc8 * 8] =
          *(const uint4*)&A[(size_t)(m0 + row) * lda + k0 + sc8 * 8];
      *(uint4*)&Ws[row * 72 + sc8 * 8] =
          *(const uint4*)&W[(size_t)(n0 + row) * ldw + k0 + sc8 * 8];
    }
    __syncthreads();
#pragma unroll
    for (int ks = 0; ks < 64; ks += 32) {
      bf16x8 af[4], bfr[4];
#pragma unroll
      for (int i = 0; i < 4; ++i)
        af[i] = *(const bf16x8*)&As[(rw + i * 16 + lrow) * 72 + ks + lk];
#pragma unroll
      for (int j = 0; j < 4; ++j)
        bfr[j] = *(const bf16x8*)&Ws[(cw + j * 16 + lrow) * 72 + ks + lk];
#pragma unroll
      for (int i = 0; i < 4; ++i)
#pragma unroll
        for (int j = 0; j < 4; ++j)
          acc[i][j] = __builtin_amdgcn_mfma_f32_16x16x32_bf16(af[i], bfr[j],
                                                              acc[i][j], 0, 0, 0);
    }
  }
  const int rsub = (lane >> 4) * 4;
#pragma unroll
  for (int i = 0; i < 4; ++i) {
#pragma unroll
    for (int j = 0; j < 4; ++j) {
      int col = n0 + cw + j * 16 + lrow;
#pragma unroll
      for (int r = 0; r < 4; ++r) {
        int row = m0 + rw + i * 16 + rsub + r;
        float v = acc[i][j][r];
        if (mode == 0) {
          Cf[(size_t)row * ldc + col] = bias ? v + bias[col] : v;
        } else if (mode == 1) {
          Cb[(size_t)row * ldc + col] = f2bf(v);
        } else {
          int tt = row >> 7, bb = row & 127;
          if (col < Ncols) {
            float o = (tt < declen[bb]) ? v + bias[col] : 0.f;
            Cf[((size_t)bb * 31 + tt) * 10000 + col] = o;
          }
        }
      }
    }
  }
}

__global__ __launch_bounds__(256) void k_mfma(
    const ushort* __restrict__ A, int lda, const ushort* __restrict__ W, int ldw,
    int K, int mode, const float* __restrict__ bias,
    float* __restrict__ Cf, ushort* __restrict__ Cb, int ldc, int Ncols,
    const int* __restrict__ declen)
{
  __shared__ ushort As[128 * 72];
  __shared__ ushort Ws[128 * 72];
  mfma_body(As, Ws, blockIdx.y, blockIdx.x, A, lda, W, ldw, K, mode, bias,
            Cf, Cb, ldc, Ncols, declen);
}

__global__ __launch_bounds__(256) void k_logits(
    const ushort* __restrict__ preA, const ushort* __restrict__ Wo,
    const float* __restrict__ b_out, float* __restrict__ out_logits,
    const int* __restrict__ declen)
{
  __shared__ ushort As[128 * 72];
  __shared__ ushort Ws[128 * 72];
  int id = blockIdx.x;
  int x = id & 7, g = id >> 3;
  int G = g / 31, row = g - G * 31;
  int col = G * 8 + x;
  if (col >= 79) return;
  mfma_body(As, Ws, row, col, preA, 512, Wo, 512, 512, 3, b_out,
            out_logits, nullptr, 10000, 10000, declen);
}

// tailhg standalone (init hp/gp from h0), 4-wave body, 32 blocks x 256 thr.
__global__ __launch_bounds__(256) void k_tailhg(
    const ushort* __restrict__ x_cur, const ushort* __restrict__ Whg,
    float* __restrict__ hgP)
{
  __shared__ ushort As[128 * 72];
  __shared__ ushort Ws[128 * 72];
  int task = blockIdx.x;
  int nt = task & 7, ks = task >> 3;
  mfma_body(As, Ws, 0, nt, x_cur + 1024 + ks * 128, 1536, Whg + ks * 128, 512,
            128, 0, nullptr, hgP + (size_t)ks * 131072, nullptr, 1024, 1024,
            nullptr);
}

// ---------------------------------------------------------------------------
// 16-wave 128x128 MFMA body (in-k_steps GEMM tasks; 1024 thr, m0=0, fp32 out).
DEV void mfma16(ushort* As, ushort* Ws, int nt,
                const ushort* __restrict__ A, int lda,
                const ushort* __restrict__ W, int ldw,
                int K, float* __restrict__ Cf, int ldc)
{
  const int tid = threadIdx.x;
  const int n0 = nt * 128;
  const int wv = tid >> 6, lane = tid & 63;
  const int rw = (wv & 3) * 32, cw = (wv >> 2) * 32;
  const int lrow = lane & 15, lk = (lane >> 4) * 8;
  f32x4 acc[2][2];
#pragma unroll
  for (int i = 0; i < 2; ++i)
#pragma unroll
    for (int j = 0; j < 2; ++j) acc[i][j] = (f32x4){0.f, 0.f, 0.f, 0.f};

  const int srow = tid >> 3;   // 0..127 (1024 thr)
  const int sc8  = tid & 7;
  for (int k0 = 0; k0 < K; k0 += 64) {
    __syncthreads();
    *(uint4*)&As[srow * 72 + sc8 * 8] =
        *(const uint4*)&A[(size_t)srow * lda + k0 + sc8 * 8];
    *(uint4*)&Ws[srow * 72 + sc8 * 8] =
        *(const uint4*)&W[(size_t)(n0 + srow) * ldw + k0 + sc8 * 8];
    __syncthreads();
#pragma unroll
    for (int ks = 0; ks < 64; ks += 32) {
      bf16x8 af[2], bfr[2];
#pragma unroll
      for (int i = 0; i < 2; ++i)
        af[i] = *(const bf16x8*)&As[(rw + i * 16 + lrow) * 72 + ks + lk];
#pragma unroll
      for (int j = 0; j < 2; ++j)
        bfr[j] = *(const bf16x8*)&Ws[(cw + j * 16 + lrow) * 72 + ks + lk];
#pragma unroll
      for (int i = 0; i < 2; ++i)
#pragma unroll
        for (int j = 0; j < 2; ++j)
          acc[i][j] = __builtin_amdgcn_mfma_f32_16x16x32_bf16(af[i], bfr[j],
                                                              acc[i][j], 0, 0, 0);
    }
  }
  const int rsub = (lane >> 4) * 4;
#pragma unroll
  for (int i = 0; i < 2; ++i)
#pragma unroll
    for (int j = 0; j < 2; ++j) {
      int col = n0 + cw + j * 16 + lrow;
#pragma unroll
      for (int r = 0; r < 4; ++r) {
        int row = rw + i * 16 + rsub + r;
        Cf[(size_t)row * ldc + col] = acc[i][j][r];
      }
    }
}

// ---------------------------------------------------------------------------
// Persistent step loop: 256 blocks x 1024 threads (16 waves, <=128 VGPR,
// one block/CU — all 256 resident, barrier-safe). Block (b=bid&127,
// half=bid>>7). 5 phases/step:
//  P1 scores-half (reduce over a-half) + preA[t-1] combine (f-half)
//  P2 softmax(dup) + alpha-out(l-half) + ctx(f-half) + gate + x_cur write
//  P3 gates GEMM (blocks 0-127: 16 nt x 8 ks, 16-wave tiles)
//  P4 lstm (tid<256/block)
//  P5 tailhg (blk 0-31, skip t=30) + pre (blk 32-63)
__global__ __launch_bounds__(1024) void k_steps(
    const ushort* __restrict__ annp_bf, const ushort* __restrict__ ann_bf,
    float* __restrict__ hgP, float* __restrict__ preP, float* __restrict__ scP,
    const float* __restrict__ b_hf, const float* __restrict__ b_beta,
    const float* __restrict__ wv, const float* __restrict__ bv,
    const int* __restrict__ captions, const float* __restrict__ E_emb,
    const int* __restrict__ declen, ushort* __restrict__ x_cur,
    ushort* __restrict__ preA_bf, float* __restrict__ out_alpha,
    const ushort* __restrict__ Wg, float* __restrict__ gP,
    const float* __restrict__ biascR, float* __restrict__ cbuf,
    const ushort* __restrict__ Whg, const ushort* __restrict__ Wcat2,
    unsigned* bar)
{
  __shared__ ushort As[128 * 72];
  __shared__ ushort Ws[128 * 72];
  __shared__ float s_hp[256];
  __shared__ float s_sc[200];
  __shared__ float s_red[32];
  __shared__ float ctxacc[16 * 256];

  const int bid = blockIdx.x;
  const int b = bid & 127, half = bid >> 7;
  const int tid = threadIdx.x, lane = tid & 63, wvx = tid >> 6;
  const float bvv = bv[0];

  for (int t = 0; t < 31; ++t) {
    // ---- P1: score partials over a-half + preA[t-1] combine ----
    if (tid < 256) {
      int a = half * 256 + tid;
      int o = b * 1024 + a;
      s_hp[tid] = b_hf[a] + hgP[o] + hgP[131072 + o] + hgP[262144 + o]
                + hgP[393216 + o];
      if (t > 0) {
        int o2 = b * 512 + a;
        float s = 0.f;
#pragma unroll
        for (int ks = 0; ks < 8; ++ks) s += preP[ks * 65536 + o2];
        preA_bf[((size_t)(t - 1) * 128 + b) * 512 + a] = f2bf(tanhf(s));
      }
    }
    __syncthreads();
    {
      float hp4[4], wt4[4];
      int a0 = half * 256 + lane * 4;
#pragma unroll
      for (int i = 0; i < 4; ++i) {
        hp4[i] = s_hp[lane * 4 + i];
        wt4[i] = wv[a0 + i];
      }
      const ushort* ap = annp_bf + (size_t)b * 196 * 512 + a0;
      us4v v[13];
#pragma unroll
      for (int k = 0; k < 13; ++k) {
        int l = wvx + 16 * k;
        int lc = (l < 196) ? l : 0;
        v[k] = *(const us4v*)(ap + (size_t)lc * 512);
      }
      float outk[13];
#pragma unroll
      for (int k = 0; k < 13; ++k) {
        float acc = 0.f;
#pragma unroll
        for (int i = 0; i < 4; ++i)
          acc = fmaf(fmaxf(bf2f(v[k][i]) + hp4[i], 0.f), wt4[i], acc);
#pragma unroll
        for (int off = 32; off; off >>= 1) acc += __shfl_xor(acc, off, 64);
        outk[k] = acc;
      }
      if (lane == 0) {
#pragma unroll
        for (int k = 0; k < 13; ++k) {
          int l = wvx + 16 * k;
          if (l < 196) scP[half * 25088 + b * 196 + l] = outk[k];
        }
      }
    }
    gbar(bar, 256);

    // ---- P2: softmax (dup per half) + alpha out + ctx f-half + x_cur ----
    {
      float vsc = -3.402823466e38f;
      if (tid < 196) {
        int o = b * 196 + tid;
        vsc = scP[o] + scP[25088 + o] + bvv;
      }
      float m = vsc;
#pragma unroll
      for (int off = 32; off; off >>= 1) m = fmaxf(m, __shfl_xor(m, off, 64));
      if (lane == 0) s_red[wvx] = m;
      __syncthreads();
      m = s_red[0];
#pragma unroll
      for (int i = 1; i < 16; ++i) m = fmaxf(m, s_red[i]);
      float e = (tid < 196) ? expf(vsc - m) : 0.f;
      float ssum = e;
#pragma unroll
      for (int off = 32; off; off >>= 1) ssum += __shfl_xor(ssum, off, 64);
      if (lane == 0) s_red[16 + wvx] = ssum;
      __syncthreads();
      float s = 0.f;
#pragma unroll
      for (int i = 0; i < 16; ++i) s += s_red[16 + i];
      float inv = 1.f / s;
      bool active = t < declen[b];
      if (tid < 196) {
        float al = e * inv;
        s_sc[tid] = al;
        if (tid >= half * 98 && tid < half * 98 + 98)
          out_alpha[((size_t)b * 31 + t) * 196 + tid] = active ? al : 0.f;
      }
      __syncthreads();
      // ctx over all l for f-half; wave wvx owns rows l = wvx + 16k
      int f0 = half * 256 + lane * 4;
      const ushort* ab = ann_bf + (size_t)b * 196 * 512 + f0;
      us4v v[13];
      float alf[13];
#pragma unroll
      for (int k = 0; k < 13; ++k) {
        int l = wvx + 16 * k;
        int lc = (l < 196) ? l : 0;
        v[k] = *(const us4v*)(ab + (size_t)lc * 512);
        alf[k] = (l < 196) ? s_sc[l] : 0.f;
      }
      float c4[4] = {0.f, 0.f, 0.f, 0.f};
#pragma unroll
      for (int k = 0; k < 13; ++k)
#pragma unroll
        for (int i = 0; i < 4; ++i)
          c4[i] = fmaf(alf[k], bf2f(v[k][i]), c4[i]);
      *(float4*)&ctxacc[wvx * 256 + lane * 4] =
          make_float4(c4[0], c4[1], c4[2], c4[3]);
      __syncthreads();
      if (tid < 256) {
        float ctx = 0.f;
#pragma unroll
        for (int w = 0; w < 16; ++w) ctx += ctxacc[w * 256 + tid];
        int fg = half * 256 + tid;
        int o2 = b * 1024 + 512 + fg;
        float g = sigmf(hgP[o2] + hgP[131072 + o2] + hgP[262144 + o2]
                        + hgP[393216 + o2] + b_beta[fg]);
        int tok = captions[b * 32 + t];
        x_cur[b * 1536 + 512 + fg] = f2bf(g * ctx);
        x_cur[b * 1536 + fg] = f2bf(E_emb[(size_t)tok * 512 + fg]);
      }
    }
    gbar(bar, 256);

    // ---- P3: gates GEMM (128 tasks = 16 nt x 8 ks, K=192) ----
    if (bid < 128) {
      int nt = bid & 15, ks = bid >> 4;
      mfma16(As, Ws, nt, x_cur + ks * 192, 1536, Wg + ks * 192, 1536, 192,
             gP + (size_t)ks * 262144, 2048);
    }
    gbar(bar, 256);

    // ---- P4: lstm (tid<256/block; idx covers 65536) ----
    if (tid < 256) {
      int idx = bid * 256 + tid;
      int bb = idx >> 9, f = idx & 511;
      if (t < declen[bb]) {
        float4 v4 = make_float4(0.f, 0.f, 0.f, 0.f);
#pragma unroll
        for (int ks = 0; ks < 8; ++ks) {
          float4 pv = *(const float4*)&gP[(size_t)ks * 262144 + bb * 2048 + f * 4];
          v4.x += pv.x; v4.y += pv.y; v4.z += pv.z; v4.w += pv.w;
        }
        float4 bc = *(const float4*)&biascR[f * 4];
        float i_ = v4.x + bc.x, f_ = v4.y + bc.y, g_ = v4.z + bc.z,
              o_ = v4.w + bc.w;
        float cn = sigmf(f_) * cbuf[idx] + sigmf(i_) * tanhf(g_);
        float hn = sigmf(o_) * tanhf(cn);
        cbuf[idx] = cn;
        x_cur[bb * 1536 + 1024 + f] = f2bf(hn);
      }
    }
    gbar(bar, 256);

    // ---- P5: tailhg (0-31, skip t=30) + pre (32-63) ----
    if (bid < 32) {
      if (t < 30) {
        int nt = bid & 7, ks = bid >> 3;
        mfma16(As, Ws, nt, x_cur + 1024 + ks * 128, 1536, Whg + ks * 128, 512,
               128, hgP + (size_t)ks * 131072, 1024);
      }
    } else if (bid < 64) {
      int j = bid - 32;
      int nt = j & 3, ks = j >> 2;
      mfma16(As, Ws, nt, x_cur + ks * 192, 1536, Wcat2 + ks * 192, 1536, 192,
             preP + (size_t)ks * 65536, 512);
    }
    gbar(bar, 256);
  }

  // epilogue: combine pre partials for t=30 (each (b,half) does its f-slice).
  if (tid < 256) {
    int f = half * 256 + tid;
    int o = b * 512 + f;
    float s = 0.f;
#pragma unroll
    for (int ks = 0; ks < 8; ++ks) s += preP[ks * 65536 + o];
    preA_bf[((size_t)30 * 128 + b) * 512 + f] = f2bf(tanhf(s));
  }
}

// ---------------------------------------------------------------------------
// Prep: weight conversions. Wg is gate-interleaved: row f*4+g <- orig row
// g*512+f of [W_ih|W_hh]; biascR likewise. Whg = [W_att_h ; W_beta].
__global__ __launch_bounds__(256) void k_prep(
    const float* __restrict__ W_ih, const float* __restrict__ W_hh,
    const float* __restrict__ b_ih, const float* __restrict__ b_hh,
    const float* __restrict__ W_y, const float* __restrict__ W_h,
    const float* __restrict__ W_z, const float* __restrict__ W_out,
    const float* __restrict__ W_att_f, const float* __restrict__ W_att_h,
    const float* __restrict__ W_beta, const float* __restrict__ b_att_f,
    const float* __restrict__ b_att_h, const float* __restrict__ ann,
    ushort* __restrict__ Wg, ushort* __restrict__ Wcat2_bf,
    ushort* __restrict__ Wo_bf, ushort* __restrict__ Waf_bf,
    ushort* __restrict__ Whg_bf, ushort* __restrict__ ann_bf,
    float* __restrict__ biascR, float* __restrict__ b_hf)
{
  int idx = blockIdx.x * 256 + threadIdx.x;
  int stride = gridDim.x * 256;
  for (int i = idx; i < 12845056 / 8; i += stride)
    cvt8(ann + (size_t)i * 8, ann_bf + (size_t)i * 8);
  for (int i = idx; i < 3145728 / 8; i += stride) {
    int k8 = i * 8, rp = k8 / 1536, c = k8 - rp * 1536;
    int f = rp >> 2, g = rp & 3;
    int r = g * 512 + f;
    const float* src = (c < 1024) ? (W_ih + (size_t)r * 1024 + c)
                                  : (W_hh + (size_t)r * 512 + c - 1024);
    cvt8(src, Wg + k8);
  }
  for (int i = idx; i < 786432 / 8; i += stride) {
    int k8 = i * 8, r = k8 / 1536, c = k8 - r * 1536;
    const float* src = (c < 512) ? (W_y + (size_t)r * 512 + c)
                     : (c < 1024 ? (W_z + (size_t)r * 512 + c - 512)
                                 : (W_h + (size_t)r * 512 + c - 1024));
    cvt8(src, Wcat2_bf + k8);
  }
  for (int i = idx; i < 5177344 / 8; i += stride) {   // Wo: 10112x512, pad 0
    int r = i >> 6, c8 = i & 63;
    if (r < 10000) cvt8(W_out + (size_t)r * 512 + c8 * 8, Wo_bf + (size_t)i * 8);
    else { *(uint4*)(Wo_bf + (size_t)i * 8) = make_uint4(0, 0, 0, 0); }
  }
  for (int i = idx; i < 262144 / 8; i += stride)
    cvt8(W_att_f + i * 8, Waf_bf + i * 8);
  for (int i = idx; i < 524288 / 8; i += stride) {    // Whg: 1024x512
    int r = i >> 6, c8 = i & 63;
    const float* src = (r < 512) ? (W_att_h + (size_t)r * 512 + c8 * 8)
                                 : (W_beta + (size_t)(r - 512) * 512 + c8 * 8);
    cvt8(src, Whg_bf + (size_t)i * 8);
  }
  for (int i = idx; i < 2048; i += stride) {
    int f = i >> 2, g = i & 3;
    biascR[i] = b_ih[g * 512 + f] + b_hh[g * 512 + f];
  }
  for (int i = idx; i < 512; i += stride) b_hf[i] = b_att_h[i] + b_att_f[i];
}

// mean over L, dec_len; also resets the grid-barrier state for this replay.
__global__ __launch_bounds__(256) void k_mean(
    const float* __restrict__ ann, const int* __restrict__ lengths,
    float* __restrict__ meanb, int* __restrict__ declen,
    float* __restrict__ out_dec, unsigned* bar)
{
  int b = blockIdx.x, tid = threadIdx.x;
  const float* ab = ann + (size_t)b * 196 * 512;
  for (int f = tid; f < 512; f += 256) {
    float s = 0.f;
    for (int l = 0; l < 196; ++l) s += ab[l * 512 + f];
    meanb[b * 512 + f] = s * (1.f / 196.f);
  }
  if (tid == 0) {
    int d = lengths[b] - 1;
    if (d < 1) d = 1;
    declen[b] = d;
    out_dec[b] = (float)d;
    if (b == 0) { bar[0] = 0u; bar[64] = 0u; }
  }
}

// fp32 32x64-tile GEMM for h0/c0 init (tiny).
DEV float actf(float v, int act) { return act == 2 ? tanhf(v) : v; }
__global__ __launch_bounds__(256) void gemm32_k(
    const float* __restrict__ A, int lda, const float* __restrict__ W, int ldw,
    const float* __restrict__ bias, float* __restrict__ C, int ldc, int K, int act)
{
  __shared__ float As[32 * 36];
  __shared__ float Ws[32 * 68];
  const int tid = threadIdx.x;
  const int m0 = blockIdx.y * 32, n0 = blockIdx.x * 64;
  const int tx = tid & 15, ty = tid >> 4;
  const int r0 = ty * 2, c0 = tx * 4;
  const int lr = tid >> 3, lk = (tid & 7) * 4;
  const float* Ap = A + (size_t)(m0 + lr) * lda + lk;
  const float* Wp0 = W + (size_t)(n0 + lr) * ldw + lk;
  const float* Wp1 = W + (size_t)(n0 + lr + 32) * ldw + lk;
  float acc[2][4] = {{0.f, 0.f, 0.f, 0.f}, {0.f, 0.f, 0.f, 0.f}};
  for (int k0 = 0; k0 < K; k0 += 32) {
    float4 av = *(const float4*)(Ap + k0);
    float4 w0 = *(const float4*)(Wp0 + k0);
    float4 w1 = *(const float4*)(Wp1 + k0);
    __syncthreads();
    As[(lk + 0) * 36 + lr] = av.x; As[(lk + 1) * 36 + lr] = av.y;
    As[(lk + 2) * 36 + lr] = av.z; As[(lk + 3) * 36 + lr] = av.w;
    Ws[(lk + 0) * 68 + lr] = w0.x; Ws[(lk + 1) * 68 + lr] = w0.y;
    Ws[(lk + 2) * 68 + lr] = w0.z; Ws[(lk + 3) * 68 + lr] = w0.w;
    Ws[(lk + 0) * 68 + lr + 32] = w1.x; Ws[(lk + 1) * 68 + lr + 32] = w1.y;
    Ws[(lk + 2) * 68 + lr + 32] = w1.z; Ws[(lk + 3) * 68 + lr + 32] = w1.w;
    __syncthreads();
#pragma unroll
    for (int kk = 0; kk < 32; ++kk) {
      float2 a = *(const float2*)&As[kk * 36 + r0];
      float4 w = *(const float4*)&Ws[kk * 68 + c0];
      const float aa[2] = {a.x, a.y};
      const float* wwp = (const float*)&w;
#pragma unroll
      for (int i = 0; i < 2; ++i)
#pragma unroll
        for (int j = 0; j < 4; ++j)
          acc[i][j] = fmaf(aa[i], wwp[j], acc[i][j]);
    }
  }
#pragma unroll
  for (int i = 0; i < 2; ++i)
#pragma unroll
    for (int j = 0; j < 4; ++j)
      C[(size_t)(m0 + r0 + i) * ldc + n0 + c0 + j] =
          actf(acc[i][j] + bias[n0 + c0 + j], act);
}

__global__ __launch_bounds__(256) void k_cvt_h0(
    const float* __restrict__ h0f, ushort* __restrict__ x_cur)
{
  int idx = blockIdx.x * 256 + threadIdx.x;   // 65536
  int b = idx >> 9, j = idx & 511;
  x_cur[b * 1536 + 1024 + j] = f2bf(h0f[idx]);
}

// ---------------------------------------------------------------------------
extern "C" void kernel_launch(void* const* d_in, const int* in_sizes, int n_in,
                              void* d_out, int out_size, void* d_ws, size_t ws_size,
                              hipStream_t stream)
{
  const float* ann      = (const float*)d_in[0];
  const int*   captions = (const int*)d_in[1];
  const int*   lengths  = (const int*)d_in[2];
  const float* E_emb    = (const float*)d_in[3];
  const float* W_init_h = (const float*)d_in[4];
  const float* b_init_h = (const float*)d_in[5];
  const float* W_init_c = (const float*)d_in[6];
  const float* b_init_c = (const float*)d_in[7];
  const float* W_att_f  = (const float*)d_in[8];
  const float* b_att_f  = (const float*)d_in[9];
  const float* W_att_h  = (const float*)d_in[10];
  const float* b_att_h  = (const float*)d_in[11];
  const float* w_att_v  = (const float*)d_in[12];
  const float* b_att_v  = (const float*)d_in[13];
  const float* W_beta   = (const float*)d_in[14];
  const float* b_beta   = (const float*)d_in[15];
  const float* W_ih     = (const float*)d_in[16];
  const float* W_hh     = (const float*)d_in[17];
  const float* b_ih     = (const float*)d_in[18];
  const float* b_hh     = (const float*)d_in[19];
  const float* W_y      = (const float*)d_in[20];
  const float* W_h      = (const float*)d_in[21];
  const float* W_z      = (const float*)d_in[22];
  const float* W_out    = (const float*)d_in[23];
  const float* b_out    = (const float*)d_in[24];

  float* out        = (float*)d_out;
  float* out_logits = out;
  float* out_alpha  = out + 39680000ll;
  float* out_dec    = out + 40457728ll;

  char* p = (char*)d_ws;
  auto alloc_us = [&](size_t n) { ushort* r = (ushort*)p; p += ((n * 2 + 255) & ~(size_t)255); return r; };
  auto alloc_f  = [&](size_t n) { float*  r = (float*)p;  p += ((n * 4 + 255) & ~(size_t)255); return r; };
  ushort* Wo_bf    = alloc_us(10112 * 512);
  ushort* Wg_bf    = alloc_us(2048 * 1536);
  ushort* Wcat2_bf = alloc_us(512 * 1536);
  ushort* Waf_bf   = alloc_us(512 * 512);
  ushort* Whg_bf   = alloc_us(1024 * 512);
  ushort* ann_bf   = alloc_us(12845056);
  ushort* annp_bf  = alloc_us(12845056);
  ushort* preA_bf  = alloc_us(3968 * 512);
  ushort* x_cur    = alloc_us(128 * 1536);
  float* biascR = alloc_f(2048);
  float* b_hf   = alloc_f(512);
  float* hgP    = alloc_f(4 * 131072);
  float* preP   = alloc_f(8 * 65536);
  float* scP    = alloc_f(2 * 128 * 196);
  float* gP     = alloc_f(8 * 262144);
  float* cbuf   = alloc_f(65536);
  float* meanb  = alloc_f(65536);
  float* h0f    = alloc_f(65536);
  int*   declen = (int*)alloc_f(128);
  unsigned* bar = (unsigned*)alloc_f(128);

  // ---- phase 1 ----
  hipLaunchKernelGGL(k_prep, dim3(1024), dim3(256), 0, stream,
                     W_ih, W_hh, b_ih, b_hh, W_y, W_h, W_z, W_out,
                     W_att_f, W_att_h, W_beta, b_att_f, b_att_h, ann,
                     Wg_bf, Wcat2_bf, Wo_bf, Waf_bf, Whg_bf, ann_bf,
                     biascR, b_hf);
  hipLaunchKernelGGL(k_mean, dim3(128), dim3(256), 0, stream,
                     ann, lengths, meanb, declen, out_dec, bar);
  hipLaunchKernelGGL(gemm32_k, dim3(8, 4), dim3(256), 0, stream,
                     meanb, 512, W_init_h, 512, b_init_h, h0f, 512, 512, 2);
  hipLaunchKernelGGL(gemm32_k, dim3(8, 4), dim3(256), 0, stream,
                     meanb, 512, W_init_c, 512, b_init_c, cbuf, 512, 512, 2);
  hipLaunchKernelGGL(k_cvt_h0, dim3(256), dim3(256), 0, stream, h0f, x_cur);
  hipLaunchKernelGGL(k_mfma, dim3(4, 196), dim3(256), 0, stream,
                     ann_bf, 512, Waf_bf, 512, 512, 1, (const float*)nullptr,
                     (float*)nullptr, annp_bf, 512, 512, (const int*)nullptr);
  // init hp/gp from h0
  hipLaunchKernelGGL(k_tailhg, dim3(32), dim3(256), 0, stream,
                     x_cur, Whg_bf, hgP);

  // ---- phase 2: 31 steps in one persistent kernel (software grid barrier) --
  hipLaunchKernelGGL(k_steps, dim3(256), dim3(1024), 0, stream,
                     annp_bf, ann_bf, hgP, preP, scP, b_hf, b_beta, w_att_v,
                     b_att_v, captions, E_emb, declen, x_cur, preA_bf,
                     out_alpha, Wg_bf, gP, biascR, cbuf, Whg_bf, Wcat2_bf, bar);

  // ---- phase 3: logits ----
  hipLaunchKernelGGL(k_logits, dim3(2480), dim3(256), 0, stream,
                     preA_bf, Wo_bf, b_out, out_logits, declen);
}

// Round 13
// 3407.392 us; speedup vs baseline: 1.8699x; 1.0053x over previous
//
#include <hip/hip_runtime.h>
#include <cstdint>

// AttentionDecoder: B=128, L=196, T_dec=31, E=H=F=A=512, V=10000
// Out: logits (128*31*10000) | alphas (128*31*196) | dec_len (128), fp32.

#define DEV __device__ __forceinline__

typedef __bf16 bf16x8 __attribute__((ext_vector_type(8)));
typedef float  f32x4  __attribute__((ext_vector_type(4)));
typedef unsigned short us4v __attribute__((ext_vector_type(4)));

DEV float sigmf(float v) { return 1.f / (1.f + expf(-v)); }

DEV ushort f2bf(float f) {
  union { float f; uint32_t u; } c; c.f = f;
  uint32_t u = c.u;
  return (ushort)((u + 0x7FFFu + ((u >> 16) & 1u)) >> 16);
}
DEV float bf2f(ushort h) {
  union { uint32_t u; float f; } c; c.u = ((uint32_t)h) << 16;
  return c.f;
}
DEV void cvt8(const float* __restrict__ s, ushort* __restrict__ d) {
  float4 a = *(const float4*)s;
  float4 b = *(const float4*)(s + 4);
  ushort4 lo = make_ushort4(f2bf(a.x), f2bf(a.y), f2bf(a.z), f2bf(a.w));
  ushort4 hi = make_ushort4(f2bf(b.x), f2bf(b.y), f2bf(b.z), f2bf(b.w));
  *(ushort4*)d = lo;
  *(ushort4*)(d + 4) = hi;
}

// Agent-coherent access helpers: relaxed agent-scope atomics compile to
// sc0=1 sc1=1 loads/stores (read-through / write-through to L3, the agent
// coherence point) — cross-XCD coherent WITHOUT any cache invalidation.
DEV float ald(const float* p) {
  return __hip_atomic_load(p, __ATOMIC_RELAXED, __HIP_MEMORY_SCOPE_AGENT);
}
DEV void ast(float* p, float v) {
  __hip_atomic_store(p, v, __ATOMIC_RELAXED, __HIP_MEMORY_SCOPE_AGENT);
}
DEV unsigned long long ald8(const void* p) {
  return __hip_atomic_load((const unsigned long long*)p, __ATOMIC_RELAXED,
                           __HIP_MEMORY_SCOPE_AGENT);
}
DEV void ast4(void* p, unsigned v) {
  __hip_atomic_store((unsigned*)p, v, __ATOMIC_RELAXED,
                     __HIP_MEMORY_SCOPE_AGENT);
}

// Software grid barrier, v3. v1 (round 5/9): ACQUIRE spin -> buffer_inv per
// poll, ~40 us/barrier. v2 (round 11): RELAXED spin + exit acquire fence ->
// 2x faster, but the per-block per-barrier buffer_inv still cold-starts L2
// every phase (FETCH stayed 2.5 GB). v3: NO exit fence at all — all
// cross-block data moves via sc1 read/write-through atomics (ald/ast above),
// so plain-load data (weights/annp/ann, read-only) stays L2-resident across
// all steps. Arrive keeps ACQ_REL fetch_add: its vmcnt wait orders the
// write-through data stores before gen is released.
// bar[0]=count, bar[64]=generation (separate cachelines).
DEV void gbar(unsigned* bar, unsigned nblk) {
  __syncthreads();
  if (threadIdx.x == 0) {
    unsigned* cnt = bar;
    unsigned* gen = bar + 64;
    unsigned g = __hip_atomic_load(gen, __ATOMIC_RELAXED, __HIP_MEMORY_SCOPE_AGENT);
    unsigned a = __hip_atomic_fetch_add(cnt, 1u, __ATOMIC_ACQ_REL,
                                        __HIP_MEMORY_SCOPE_AGENT);
    if (a == nblk - 1u) {
      __hip_atomic_store(cnt, 0u, __ATOMIC_RELAXED, __HIP_MEMORY_SCOPE_AGENT);
      __hip_atomic_store(gen, g + 1u, __ATOMIC_RELEASE, __HIP_MEMORY_SCOPE_AGENT);
    } else {
      while (__hip_atomic_load(gen, __ATOMIC_RELAXED,
                               __HIP_MEMORY_SCOPE_AGENT) == g)
        __builtin_amdgcn_s_sleep(2);
    }
  }
  __syncthreads();
}

// ---------------------------------------------------------------------------
// 4-wave 128x128 MFMA body (standalone kernels: annp GEMM, logits, init).
DEV void mfma_body(ushort* As, ushort* Ws, int mt, int nt,
                   const ushort* __restrict__ A, int lda,
                   const ushort* __restrict__ W, int ldw,
                   int K, int mode, const float* __restrict__ bias,
                   float* __restrict__ Cf, ushort* __restrict__ Cb, int ldc,
                   int Ncols, const int* __restrict__ declen)
{
  const int tid = threadIdx.x;
  const int m0 = mt * 128, n0 = nt * 128;
  const int wv = tid >> 6, lane = tid & 63;
  const int rw = (wv & 1) * 64, cw = (wv >> 1) * 64;
  const int lrow = lane & 15, lk = (lane >> 4) * 8;
  f32x4 acc[4][4];
#pragma unroll
  for (int i = 0; i < 4; ++i)
#pragma unroll
    for (int j = 0; j < 4; ++j) acc[i][j] = (f32x4){0.f, 0.f, 0.f, 0.f};

  const int srow = tid >> 3;
  const int sc8  = tid & 7;
  for (int k0 = 0; k0 < K; k0 += 64) {
    __syncthreads();
#pragma unroll
    for (int it = 0; it < 4; ++it) {
      int row = it * 32 + srow;
      *(uint4*)&As[row * 72 + sc8 * 8] =
          *(const uint4*)&A[(size_t)(m0 + row) * lda + k0 + sc8 * 8];
      *(uint4*)&Ws[row * 72 + sc8 * 8] =
          *(const uint4*)&W[(size_t)(n0 + row) * ldw + k0 + sc8 * 8];
    }
    __syncthreads();
#pragma unroll
    for (int ks = 0; ks < 64; ks += 32) {
      bf16x8 af[4], bfr[4];
#pragma unroll
      for (int i = 0; i < 4; ++i)
        af[i] = *(const bf16x8*)&As[(rw + i * 16 + lrow) * 72 + ks + lk];
#pragma unroll
      for (int j = 0; j < 4; ++j)
        bfr[j] = *(const bf16x8*)&Ws[(cw + j * 16 + lrow) * 72 + ks + lk];
#pragma unroll
      for (int i = 0; i < 4; ++i)
#pragma unroll
        for (int j = 0; j < 4; ++j)
          acc[i][j] = __builtin_amdgcn_mfma_f32_16x16x32_bf16(af[i], bfr[j],
                                                              acc[i][j], 0, 0, 0);
    }
  }
  const int rsub = (lane >> 4) * 4;
#pragma unroll
  for (int i = 0; i < 4; ++i) {
#pragma unroll
    for (int j = 0; j < 4; ++j) {
      int col = n0 + cw + j * 16 + lrow;
#pragma unroll
      for (int r = 0; r < 4; ++r) {
        int row = m0 + rw + i * 16 + rsub + r;
        float v = acc[i][j][r];
        if (mode == 0) {
          Cf[(size_t)row * ldc + col] = bias ? v + bias[col] : v;
        } else if (mode == 1) {
          Cb[(size_t)row * ldc + col] = f2bf(v);
        } else {
          int tt = row >> 7, bb = row & 127;
          if (col < Ncols) {
            float o = (tt < declen[bb]) ? v + bias[col] : 0.f;
            Cf[((size_t)bb * 31 + tt) * 10000 + col] = o;
          }
        }
      }
    }
  }
}

__global__ __launch_bounds__(256) void k_mfma(
    const ushort* __restrict__ A, int lda, const ushort* __restrict__ W, int ldw,
    int K, int mode, const float* __restrict__ bias,
    float* __restrict__ Cf, ushort* __restrict__ Cb, int ldc, int Ncols,
    const int* __restrict__ declen)
{
  __shared__ ushort As[128 * 72];
  __shared__ ushort Ws[128 * 72];
  mfma_body(As, Ws, blockIdx.y, blockIdx.x, A, lda, W, ldw, K, mode, bias,
            Cf, Cb, ldc, Ncols, declen);
}

__global__ __launch_bounds__(256) void k_logits(
    const ushort* __restrict__ preA, const ushort* __restrict__ Wo,
    const float* __restrict__ b_out, float* __restrict__ out_logits,
    const int* __restrict__ declen)
{
  __shared__ ushort As[128 * 72];
  __shared__ ushort Ws[128 * 72];
  int id = blockIdx.x;
  int x = id & 7, g = id >> 3;
  int G = g / 31, row = g - G * 31;
  int col = G * 8 + x;
  if (col >= 79) return;
  mfma_body(As, Ws, row, col, preA, 512, Wo, 512, 512, 3, b_out,
            out_logits, nullptr, 10000, 10000, declen);
}

// tailhg standalone (init hp/gp from h0), 4-wave body, 32 blocks x 256 thr.
__global__ __launch_bounds__(256) void k_tailhg(
    const ushort* __restrict__ x_cur, const ushort* __restrict__ Whg,
    float* __restrict__ hgP)
{
  __shared__ ushort As[128 * 72];
  __shared__ ushort Ws[128 * 72];
  int task = blockIdx.x;
  int nt = task & 7, ks = task >> 3;
  mfma_body(As, Ws, 0, nt, x_cur + 1024 + ks * 128, 1536, Whg + ks * 128, 512,
            128, 0, nullptr, hgP + (size_t)ks * 131072, nullptr, 1024, 1024,
            nullptr);
}

// ---------------------------------------------------------------------------
// 16-wave 128x128 MFMA body for in-k_steps GEMMs (1024 thr, m0=0, fp32 out).
// A (x_cur) is cross-block data -> sc1 coherent 8B loads; W is read-only
// weights -> plain (L2-cached); C partials are cross-block -> sc1 stores.
DEV void mfma16(ushort* As, ushort* Ws, int nt,
                const ushort* A, int lda,
                const ushort* __restrict__ W, int ldw,
                int K, float* Cf, int ldc)
{
  const int tid = threadIdx.x;
  const int n0 = nt * 128;
  const int wv = tid >> 6, lane = tid & 63;
  const int rw = (wv & 3) * 32, cw = (wv >> 2) * 32;
  const int lrow = lane & 15, lk = (lane >> 4) * 8;
  f32x4 acc[2][2];
#pragma unroll
  for (int i = 0; i < 2; ++i)
#pragma unroll
    for (int j = 0; j < 2; ++j) acc[i][j] = (f32x4){0.f, 0.f, 0.f, 0.f};

  const int srow = tid >> 3;   // 0..127 (1024 thr)
  const int sc8  = tid & 7;
  for (int k0 = 0; k0 < K; k0 += 64) {
    __syncthreads();
    {
      const ushort* ap = &A[(size_t)srow * lda + k0 + sc8 * 8];
      unsigned long long lo = ald8(ap);
      unsigned long long hi = ald8(ap + 4);
      *(unsigned long long*)&As[srow * 72 + sc8 * 8] = lo;
      *(unsigned long long*)&As[srow * 72 + sc8 * 8 + 4] = hi;
    }
    *(uint4*)&Ws[srow * 72 + sc8 * 8] =
        *(const uint4*)&W[(size_t)(n0 + srow) * ldw + k0 + sc8 * 8];
    __syncthreads();
#pragma unroll
    for (int ks = 0; ks < 64; ks += 32) {
      bf16x8 af[2], bfr[2];
#pragma unroll
      for (int i = 0; i < 2; ++i)
        af[i] = *(const bf16x8*)&As[(rw + i * 16 + lrow) * 72 + ks + lk];
#pragma unroll
      for (int j = 0; j < 2; ++j)
        bfr[j] = *(const bf16x8*)&Ws[(cw + j * 16 + lrow) * 72 + ks + lk];
#pragma unroll
      for (int i = 0; i < 2; ++i)
#pragma unroll
        for (int j = 0; j < 2; ++j)
          acc[i][j] = __builtin_amdgcn_mfma_f32_16x16x32_bf16(af[i], bfr[j],
                                                              acc[i][j], 0, 0, 0);
    }
  }
  const int rsub = (lane >> 4) * 4;
#pragma unroll
  for (int i = 0; i < 2; ++i)
#pragma unroll
    for (int j = 0; j < 2; ++j) {
      int col = n0 + cw + j * 16 + lrow;
#pragma unroll
      for (int r = 0; r < 4; ++r) {
        int row = rw + i * 16 + rsub + r;
        ast(&Cf[(size_t)row * ldc + col], acc[i][j][r]);
      }
    }
}

// ---------------------------------------------------------------------------
// Persistent step loop: 256 blocks x 1024 threads (16 waves, <=128 VGPR).
// Block (b=bid&127, half=bid>>7). 5 phases/step:
//  P1 scores-half (reduce over a-half) + preA[t-1] combine (f-half)
//  P2 softmax(dup) + alpha-out(l-half) + ctx(f-half) + gate + x_cur write
//  P3 gates GEMM (blocks 0-127: 16 nt x 8 ks, 16-wave tiles)
//  P4 lstm (128 thr/block, 2 elems each)
//  P5 tailhg (blk 0-31, skip t=30) + pre (blk 32-63)
// Cross-block buffers (scP, x_cur, gP, hgP, preP) via sc1 atomics; weights /
// annp / ann via plain loads (stay L2-resident — no invalidation anywhere).
__global__ __launch_bounds__(1024) void k_steps(
    const ushort* __restrict__ annp_bf, const ushort* __restrict__ ann_bf,
    float* hgP, float* preP, float* scP,
    const float* __restrict__ b_hf, const float* __restrict__ b_beta,
    const float* __restrict__ wv, const float* __restrict__ bv,
    const int* __restrict__ captions, const float* __restrict__ E_emb,
    const int* __restrict__ declen, ushort* x_cur,
    ushort* __restrict__ preA_bf, float* __restrict__ out_alpha,
    const ushort* __restrict__ Wg, float* gP,
    const float* __restrict__ biascR, float* __restrict__ cbuf,
    const ushort* __restrict__ Whg, const ushort* __restrict__ Wcat2,
    unsigned* bar)
{
  __shared__ ushort As[128 * 72];
  __shared__ ushort Ws[128 * 72];
  __shared__ float s_hp[256];
  __shared__ float s_sc[200];
  __shared__ float s_red[32];
  __shared__ float ctxacc[16 * 256];

  const int bid = blockIdx.x;
  const int b = bid & 127, half = bid >> 7;
  const int tid = threadIdx.x, lane = tid & 63, wvx = tid >> 6;
  const float bvv = bv[0];

  for (int t = 0; t < 31; ++t) {
    // ---- P1: score partials over a-half + preA[t-1] combine ----
    if (tid < 256) {
      int a = half * 256 + tid;
      int o = b * 1024 + a;
      s_hp[tid] = b_hf[a] + ald(&hgP[o]) + ald(&hgP[131072 + o])
                + ald(&hgP[262144 + o]) + ald(&hgP[393216 + o]);
      if (t > 0) {
        int o2 = b * 512 + a;
        float s = 0.f;
#pragma unroll
        for (int ks = 0; ks < 8; ++ks) s += ald(&preP[ks * 65536 + o2]);
        preA_bf[((size_t)(t - 1) * 128 + b) * 512 + a] = f2bf(tanhf(s));
      }
    }
    __syncthreads();
    {
      float hp4[4], wt4[4];
      int a0 = half * 256 + lane * 4;
#pragma unroll
      for (int i = 0; i < 4; ++i) {
        hp4[i] = s_hp[lane * 4 + i];
        wt4[i] = wv[a0 + i];
      }
      const ushort* ap = annp_bf + (size_t)b * 196 * 512 + a0;
      us4v v[13];
#pragma unroll
      for (int k = 0; k < 13; ++k) {
        int l = wvx + 16 * k;
        int lc = (l < 196) ? l : 0;
        v[k] = *(const us4v*)(ap + (size_t)lc * 512);
      }
      float outk[13];
#pragma unroll
      for (int k = 0; k < 13; ++k) {
        float acc = 0.f;
#pragma unroll
        for (int i = 0; i < 4; ++i)
          acc = fmaf(fmaxf(bf2f(v[k][i]) + hp4[i], 0.f), wt4[i], acc);
#pragma unroll
        for (int off = 32; off; off >>= 1) acc += __shfl_xor(acc, off, 64);
        outk[k] = acc;
      }
      if (lane == 0) {
#pragma unroll
        for (int k = 0; k < 13; ++k) {
          int l = wvx + 16 * k;
          if (l < 196) ast(&scP[half * 25088 + b * 196 + l], outk[k]);
        }
      }
    }
    gbar(bar, 256);

    // ---- P2: softmax (dup per half) + alpha out + ctx f-half + x_cur ----
    {
      float vsc = -3.402823466e38f;
      if (tid < 196) {
        int o = b * 196 + tid;
        vsc = ald(&scP[o]) + ald(&scP[25088 + o]) + bvv;
      }
      float m = vsc;
#pragma unroll
      for (int off = 32; off; off >>= 1) m = fmaxf(m, __shfl_xor(m, off, 64));
      if (lane == 0) s_red[wvx] = m;
      __syncthreads();
      m = s_red[0];
#pragma unroll
      for (int i = 1; i < 16; ++i) m = fmaxf(m, s_red[i]);
      float e = (tid < 196) ? expf(vsc - m) : 0.f;
      float ssum = e;
#pragma unroll
      for (int off = 32; off; off >>= 1) ssum += __shfl_xor(ssum, off, 64);
      if (lane == 0) s_red[16 + wvx] = ssum;
      __syncthreads();
      float s = 0.f;
#pragma unroll
      for (int i = 0; i < 16; ++i) s += s_red[16 + i];
      float inv = 1.f / s;
      bool active = t < declen[b];
      if (tid < 196) {
        float al = e * inv;
        s_sc[tid] = al;
        if (tid >= half * 98 && tid < half * 98 + 98)
          out_alpha[((size_t)b * 31 + t) * 196 + tid] = active ? al : 0.f;
      }
      __syncthreads();
      // ctx over all l for f-half; wave wvx owns rows l = wvx + 16k
      int f0 = half * 256 + lane * 4;
      const ushort* ab = ann_bf + (size_t)b * 196 * 512 + f0;
      us4v v[13];
      float alf[13];
#pragma unroll
      for (int k = 0; k < 13; ++k) {
        int l = wvx + 16 * k;
        int lc = (l < 196) ? l : 0;
        v[k] = *(const us4v*)(ab + (size_t)lc * 512);
        alf[k] = (l < 196) ? s_sc[l] : 0.f;
      }
      float c4[4] = {0.f, 0.f, 0.f, 0.f};
#pragma unroll
      for (int k = 0; k < 13; ++k)
#pragma unroll
        for (int i = 0; i < 4; ++i)
          c4[i] = fmaf(alf[k], bf2f(v[k][i]), c4[i]);
      *(float4*)&ctxacc[wvx * 256 + lane * 4] =
          make_float4(c4[0], c4[1], c4[2], c4[3]);
      __syncthreads();
      if (tid < 128) {
        int j0 = tid * 2;
        float ctx0 = 0.f, ctx1 = 0.f;
#pragma unroll
        for (int w = 0; w < 16; ++w) {
          ctx0 += ctxacc[w * 256 + j0];
          ctx1 += ctxacc[w * 256 + j0 + 1];
        }
        int fg0 = half * 256 + j0;
        int o2 = b * 1024 + 512 + fg0;
        float g0 = sigmf(ald(&hgP[o2]) + ald(&hgP[131072 + o2])
                       + ald(&hgP[262144 + o2]) + ald(&hgP[393216 + o2])
                       + b_beta[fg0]);
        float g1 = sigmf(ald(&hgP[o2 + 1]) + ald(&hgP[131072 + o2 + 1])
                       + ald(&hgP[262144 + o2 + 1]) + ald(&hgP[393216 + o2 + 1])
                       + b_beta[fg0 + 1]);
        int tok = captions[b * 32 + t];
        unsigned gc = (unsigned)f2bf(g0 * ctx0)
                    | ((unsigned)f2bf(g1 * ctx1) << 16);
        unsigned eb = (unsigned)f2bf(E_emb[(size_t)tok * 512 + fg0])
                    | ((unsigned)f2bf(E_emb[(size_t)tok * 512 + fg0 + 1]) << 16);
        ast4(&x_cur[b * 1536 + 512 + fg0], gc);
        ast4(&x_cur[b * 1536 + fg0], eb);
      }
    }
    gbar(bar, 256);

    // ---- P3: gates GEMM (128 tasks = 16 nt x 8 ks, K=192) ----
    if (bid < 128) {
      int nt = bid & 15, ks = bid >> 4;
      mfma16(As, Ws, nt, x_cur + ks * 192, 1536, Wg + ks * 192, 1536, 192,
             gP + (size_t)ks * 262144, 2048);
    }
    gbar(bar, 256);

    // ---- P4: lstm (128 thr/block, 2 consecutive f each; 65536 total) ----
    if (tid < 128) {
      int idx0 = bid * 256 + tid * 2;
      int bb = idx0 >> 9, f0 = idx0 & 511;
      if (t < declen[bb]) {
        float s0[4] = {0.f, 0.f, 0.f, 0.f};
        float s1[4] = {0.f, 0.f, 0.f, 0.f};
#pragma unroll
        for (int ks = 0; ks < 8; ++ks) {
          const float* gpb = &gP[(size_t)ks * 262144 + bb * 2048 + f0 * 4];
#pragma unroll
          for (int q = 0; q < 4; ++q) {
            union { unsigned long long u; float f[2]; } c;
            c.u = ald8(gpb + q * 2);
            if (q < 2) { s0[q * 2] += c.f[0]; s0[q * 2 + 1] += c.f[1]; }
            else { s1[(q - 2) * 2] += c.f[0]; s1[(q - 2) * 2 + 1] += c.f[1]; }
          }
        }
        float4 bc0 = *(const float4*)&biascR[f0 * 4];
        float4 bc1 = *(const float4*)&biascR[(f0 + 1) * 4];
        float i0 = s0[0] + bc0.x, ff0 = s0[1] + bc0.y,
              g0 = s0[2] + bc0.z, o0 = s0[3] + bc0.w;
        float i1 = s1[0] + bc1.x, ff1 = s1[1] + bc1.y,
              g1 = s1[2] + bc1.z, o1 = s1[3] + bc1.w;
        float cn0 = sigmf(ff0) * cbuf[idx0] + sigmf(i0) * tanhf(g0);
        float hn0 = sigmf(o0) * tanhf(cn0);
        float cn1 = sigmf(ff1) * cbuf[idx0 + 1] + sigmf(i1) * tanhf(g1);
        float hn1 = sigmf(o1) * tanhf(cn1);
        cbuf[idx0] = cn0;
        cbuf[idx0 + 1] = cn1;
        unsigned hp = (unsigned)f2bf(hn0) | ((unsigned)f2bf(hn1) << 16);
        ast4(&x_cur[bb * 1536 + 1024 + f0], hp);
      }
    }
    gbar(bar, 256);

    // ---- P5: tailhg (0-31, skip t=30) + pre (32-63) ----
    if (bid < 32) {
      if (t < 30) {
        int nt = bid & 7, ks = bid >> 3;
        mfma16(As, Ws, nt, x_cur + 1024 + ks * 128, 1536, Whg + ks * 128, 512,
               128, hgP + (size_t)ks * 131072, 1024);
      }
    } else if (bid < 64) {
      int j = bid - 32;
      int nt = j & 3, ks = j >> 2;
      mfma16(As, Ws, nt, x_cur + ks * 192, 1536, Wcat2 + ks * 192, 1536, 192,
             preP + (size_t)ks * 65536, 512);
    }
    gbar(bar, 256);
  }

  // epilogue: combine pre partials for t=30 (each (b,half) does its f-slice).
  if (tid < 256) {
    int f = half * 256 + tid;
    int o = b * 512 + f;
    float s = 0.f;
#pragma unroll
    for (int ks = 0; ks < 8; ++ks) s += ald(&preP[ks * 65536 + o]);
    preA_bf[((size_t)30 * 128 + b) * 512 + f] = f2bf(tanhf(s));
  }
}

// ---------------------------------------------------------------------------
// Prep: weight conversions. Wg is gate-interleaved: row f*4+g <- orig row
// g*512+f of [W_ih|W_hh]; biascR likewise. Whg = [W_att_h ; W_beta].
__global__ __launch_bounds__(256) void k_prep(
    const float* __restrict__ W_ih, const float* __restrict__ W_hh,
    const float* __restrict__ b_ih, const float* __restrict__ b_hh,
    const float* __restrict__ W_y, const float* __restrict__ W_h,
    const float* __restrict__ W_z, const float* __restrict__ W_out,
    const float* __restrict__ W_att_f, const float* __restrict__ W_att_h,
    const float* __restrict__ W_beta, const float* __restrict__ b_att_f,
    const float* __restrict__ b_att_h, const float* __restrict__ ann,
    ushort* __restrict__ Wg, ushort* __restrict__ Wcat2_bf,
    ushort* __restrict__ Wo_bf, ushort* __restrict__ Waf_bf,
    ushort* __restrict__ Whg_bf, ushort* __restrict__ ann_bf,
    float* __restrict__ biascR, float* __restrict__ b_hf)
{
  int idx = blockIdx.x * 256 + threadIdx.x;
  int stride = gridDim.x * 256;
  for (int i = idx; i < 12845056 / 8; i += stride)
    cvt8(ann + (size_t)i * 8, ann_bf + (size_t)i * 8);
  for (int i = idx; i < 3145728 / 8; i += stride) {
    int k8 = i * 8, rp = k8 / 1536, c = k8 - rp * 1536;
    int f = rp >> 2, g = rp & 3;
    int r = g * 512 + f;
    const float* src = (c < 1024) ? (W_ih + (size_t)r * 1024 + c)
                                  : (W_hh + (size_t)r * 512 + c - 1024);
    cvt8(src, Wg + k8);
  }
  for (int i = idx; i < 786432 / 8; i += stride) {
    int k8 = i * 8, r = k8 / 1536, c = k8 - r * 1536;
    const float* src = (c < 512) ? (W_y + (size_t)r * 512 + c)
                     : (c < 1024 ? (W_z + (size_t)r * 512 + c - 512)
                                 : (W_h + (size_t)r * 512 + c - 1024));
    cvt8(src, Wcat2_bf + k8);
  }
  for (int i = idx; i < 5177344 / 8; i += stride) {   // Wo: 10112x512, pad 0
    int r = i >> 6, c8 = i & 63;
    if (r < 10000) cvt8(W_out + (size_t)r * 512 + c8 * 8, Wo_bf + (size_t)i * 8);
    else { *(uint4*)(Wo_bf + (size_t)i * 8) = make_uint4(0, 0, 0, 0); }
  }
  for (int i = idx; i < 262144 / 8; i += stride)
    cvt8(W_att_f + i * 8, Waf_bf + i * 8);
  for (int i = idx; i < 524288 / 8; i += stride) {    // Whg: 1024x512
    int r = i >> 6, c8 = i & 63;
    const float* src = (r < 512) ? (W_att_h + (size_t)r * 512 + c8 * 8)
                                 : (W_beta + (size_t)(r - 512) * 512 + c8 * 8);
    cvt8(src, Whg_bf + (size_t)i * 8);
  }
  for (int i = idx; i < 2048; i += stride) {
    int f = i >> 2, g = i & 3;
    biascR[i] = b_ih[g * 512 + f] + b_hh[g * 512 + f];
  }
  for (int i = idx; i < 512; i += stride) b_hf[i] = b_att_h[i] + b_att_f[i];
}

// mean over L, dec_len; also resets the grid-barrier state for this replay.
__global__ __launch_bounds__(256) void k_mean(
    const float* __restrict__ ann, const int* __restrict__ lengths,
    float* __restrict__ meanb, int* __restrict__ declen,
    float* __restrict__ out_dec, unsigned* bar)
{
  int b = blockIdx.x, tid = threadIdx.x;
  const float* ab = ann + (size_t)b * 196 * 512;
  for (int f = tid; f < 512; f += 256) {
    float s = 0.f;
    for (int l = 0; l < 196; ++l) s += ab[l * 512 + f];
    meanb[b * 512 + f] = s * (1.f / 196.f);
  }
  if (tid == 0) {
    int d = lengths[b] - 1;
    if (d < 1) d = 1;
    declen[b] = d;
    out_dec[b] = (float)d;
    if (b == 0) { bar[0] = 0u; bar[64] = 0u; }
  }
}

// fp32 32x64-tile GEMM for h0/c0 init (tiny).
DEV float actf(float v, int act) { return act == 2 ? tanhf(v) : v; }
__global__ __launch_bounds__(256) void gemm32_k(
    const float* __restrict__ A, int lda, const float* __restrict__ W, int ldw,
    const float* __restrict__ bias, float* __restrict__ C, int ldc, int K, int act)
{
  __shared__ float As[32 * 36];
  __shared__ float Ws[32 * 68];
  const int tid = threadIdx.x;
  const int m0 = blockIdx.y * 32, n0 = blockIdx.x * 64;
  const int tx = tid & 15, ty = tid >> 4;
  const int r0 = ty * 2, c0 = tx * 4;
  const int lr = tid >> 3, lk = (tid & 7) * 4;
  const float* Ap = A + (size_t)(m0 + lr) * lda + lk;
  const float* Wp0 = W + (size_t)(n0 + lr) * ldw + lk;
  const float* Wp1 = W + (size_t)(n0 + lr + 32) * ldw + lk;
  float acc[2][4] = {{0.f, 0.f, 0.f, 0.f}, {0.f, 0.f, 0.f, 0.f}};
  for (int k0 = 0; k0 < K; k0 += 32) {
    float4 av = *(const float4*)(Ap + k0);
    float4 w0 = *(const float4*)(Wp0 + k0);
    float4 w1 = *(const float4*)(Wp1 + k0);
    __syncthreads();
    As[(lk + 0) * 36 + lr] = av.x; As[(lk + 1) * 36 + lr] = av.y;
    As[(lk + 2) * 36 + lr] = av.z; As[(lk + 3) * 36 + lr] = av.w;
    Ws[(lk + 0) * 68 + lr] = w0.x; Ws[(lk + 1) * 68 + lr] = w0.y;
    Ws[(lk + 2) * 68 + lr] = w0.z; Ws[(lk + 3) * 68 + lr] = w0.w;
    Ws[(lk + 0) * 68 + lr + 32] = w1.x; Ws[(lk + 1) * 68 + lr + 32] = w1.y;
    Ws[(lk + 2) * 68 + lr + 32] = w1.z; Ws[(lk + 3) * 68 + lr + 32] = w1.w;
    __syncthreads();
#pragma unroll
    for (int kk = 0; kk < 32; ++kk) {
      float2 a = *(const float2*)&As[kk * 36 + r0];
      float4 w = *(const float4*)&Ws[kk * 68 + c0];
      const float aa[2] = {a.x, a.y};
      const float* wwp = (const float*)&w;
#pragma unroll
      for (int i = 0; i < 2; ++i)
#pragma unroll
        for (int j = 0; j < 4; ++j)
          acc[i][j] = fmaf(aa[i], wwp[j], acc[i][j]);
    }
  }
#pragma unroll
  for (int i = 0; i < 2; ++i)
#pragma unroll
    for (int j = 0; j < 4; ++j)
      C[(size_t)(m0 + r0 + i) * ldc + n0 + c0 + j] =
          actf(acc[i][j] + bias[n0 + c0 + j], act);
}

__global__ __launch_bounds__(256) void k_cvt_h0(
    const float* __restrict__ h0f, ushort* __restrict__ x_cur)
{
  int idx = blockIdx.x * 256 + threadIdx.x;   // 65536
  int b = idx >> 9, j = idx & 511;
  x_cur[b * 1536 + 1024 + j] = f2bf(h0f[idx]);
}

// ---------------------------------------------------------------------------
extern "C" void kernel_launch(void* const* d_in, const int* in_sizes, int n_in,
                              void* d_out, int out_size, void* d_ws, size_t ws_size,
                              hipStream_t stream)
{
  const float* ann      = (const float*)d_in[0];
  const int*   captions = (const int*)d_in[1];
  const int*   lengths  = (const int*)d_in[2];
  const float* E_emb    = (const float*)d_in[3];
  const float* W_init_h = (const float*)d_in[4];
  const float* b_init_h = (const float*)d_in[5];
  const float* W_init_c = (const float*)d_in[6];
  const float* b_init_c = (const float*)d_in[7];
  const float* W_att_f  = (const float*)d_in[8];
  const float* b_att_f  = (const float*)d_in[9];
  const float* W_att_h  = (const float*)d_in[10];
  const float* b_att_h  = (const float*)d_in[11];
  const float* w_att_v  = (const float*)d_in[12];
  const float* b_att_v  = (const float*)d_in[13];
  const float* W_beta   = (const float*)d_in[14];
  const float* b_beta   = (const float*)d_in[15];
  const float* W_ih     = (const float*)d_in[16];
  const float* W_hh     = (const float*)d_in[17];
  const float* b_ih     = (const float*)d_in[18];
  const float* b_hh     = (const float*)d_in[19];
  const float* W_y      = (const float*)d_in[20];
  const float* W_h      = (const float*)d_in[21];
  const float* W_z      = (const float*)d_in[22];
  const float* W_out    = (const float*)d_in[23];
  const float* b_out    = (const float*)d_in[24];

  float* out        = (float*)d_out;
  float* out_logits = out;
  float* out_alpha  = out + 39680000ll;
  float* out_dec    = out + 40457728ll;

  char* p = (char*)d_ws;
  auto alloc_us = [&](size_t n) { ushort* r = (ushort*)p; p += ((n * 2 + 255) & ~(size_t)255); return r; };
  auto alloc_f  = [&](size_t n) { float*  r = (float*)p;  p += ((n * 4 + 255) & ~(size_t)255); return r; };
  ushort* Wo_bf    = alloc_us(10112 * 512);
  ushort* Wg_bf    = alloc_us(2048 * 1536);
  ushort* Wcat2_bf = alloc_us(512 * 1536);
  ushort* Waf_bf   = alloc_us(512 * 512);
  ushort* Whg_bf   = alloc_us(1024 * 512);
  ushort* ann_bf   = alloc_us(12845056);
  ushort* annp_bf  = alloc_us(12845056);
  ushort* preA_bf  = alloc_us(3968 * 512);
  ushort* x_cur    = alloc_us(128 * 1536);
  float* biascR = alloc_f(2048);
  float* b_hf   = alloc_f(512);
  float* hgP    = alloc_f(4 * 131072);
  float* preP   = alloc_f(8 * 65536);
  float* scP    = alloc_f(2 * 128 * 196);
  float* gP     = alloc_f(8 * 262144);
  float* cbuf   = alloc_f(65536);
  float* meanb  = alloc_f(65536);
  float* h0f    = alloc_f(65536);
  int*   declen = (int*)alloc_f(128);
  unsigned* bar = (unsigned*)alloc_f(128);

  // ---- phase 1 ----
  hipLaunchKernelGGL(k_prep, dim3(1024), dim3(256), 0, stream,
                     W_ih, W_hh, b_ih, b_hh, W_y, W_h, W_z, W_out,
                     W_att_f, W_att_h, W_beta, b_att_f, b_att_h, ann,
                     Wg_bf, Wcat2_bf, Wo_bf, Waf_bf, Whg_bf, ann_bf,
                     biascR, b_hf);
  hipLaunchKernelGGL(k_mean, dim3(128), dim3(256), 0, stream,
                     ann, lengths, meanb, declen, out_dec, bar);
  hipLaunchKernelGGL(gemm32_k, dim3(8, 4), dim3(256), 0, stream,
                     meanb, 512, W_init_h, 512, b_init_h, h0f, 512, 512, 2);
  hipLaunchKernelGGL(gemm32_k, dim3(8, 4), dim3(256), 0, stream,
                     meanb, 512, W_init_c, 512, b_init_c, cbuf, 512, 512, 2);
  hipLaunchKernelGGL(k_cvt_h0, dim3(256), dim3(256), 0, stream, h0f, x_cur);
  hipLaunchKernelGGL(k_mfma, dim3(4, 196), dim3(256), 0, stream,
                     ann_bf, 512, Waf_bf, 512, 512, 1, (const float*)nullptr,
                     (float*)nullptr, annp_bf, 512, 512, (const int*)nullptr);
  // init hp/gp from h0
  hipLaunchKernelGGL(k_tailhg, dim3(32), dim3(256), 0, stream,
                     x_cur, Whg_bf, hgP);

  // ---- phase 2: 31 steps in one persistent kernel (software grid barrier) --
  hipLaunchKernelGGL(k_steps, dim3(256), dim3(1024), 0, stream,
                     annp_bf, ann_bf, hgP, preP, scP, b_hf, b_beta, w_att_v,
                     b_att_v, captions, E_emb, declen, x_cur, preA_bf,
                     out_alpha, Wg_bf, gP, biascR, cbuf, Whg_bf, Wcat2_bf, bar);

  // ---- phase 3: logits ----
  hipLaunchKernelGGL(k_logits, dim3(2480), dim3(256), 0, stream,
                     preA_bf, Wo_bf, b_out, out_logits, declen);
}